// Round 7
// baseline (267.191 us; speedup 1.0000x reference)
//
#include <hip/hip_runtime.h>
#include <hip/hip_bf16.h>

typedef __attribute__((ext_vector_type(4))) float f32x4;
typedef __attribute__((ext_vector_type(16))) float f32x16;
typedef __attribute__((ext_vector_type(8))) short short8;

#define D_MODEL 512
#define SQ 2048
#define NH 8
#define NBATCH 4
#define MROWS (NBATCH * SQ)  // 8192

// split-K chunking: per qi (0..15), T=4*qi+4 tiles split into nch=(qi+2)>>1
// balanced chunks (sizes 4..8). Blocks per (n,h) = sum nch = 72.
#define CHUNKS_PER_NH 72
#define NSLOTS (32 * CHUNKS_PER_NH)  // 2304

__device__ __forceinline__ ushort f2b(float x) {
  unsigned int u = __float_as_uint(x);
  return (ushort)((u + 0x7fffu + ((u >> 16) & 1u)) >> 16);
}

__device__ __forceinline__ f32x4 mfma16(short8 a, short8 b, f32x4 c) {
  return __builtin_amdgcn_mfma_f32_16x16x32_bf16(a, b, c, 0, 0, 0);
}
__device__ __forceinline__ f32x16 mfma32(short8 a, short8 b, f32x16 c) {
  return __builtin_amdgcn_mfma_f32_32x32x16_bf16(a, b, c, 0, 0, 0);
}

#define GLOAD_LDS16(g, l)                                                      \
  __builtin_amdgcn_global_load_lds(                                            \
      (const __attribute__((address_space(1))) unsigned int*)(g),              \
      (__attribute__((address_space(3))) unsigned int*)(l), 16, 0, 0)

// ---------------------------------------------------------------------------
// Weight transpose + fp32 -> bf16 cast:  W[K][N] -> WT[N][K] (bf16)
// ---------------------------------------------------------------------------
__global__ __launch_bounds__(256) void transpose_w(const float* __restrict__ W,
                                                   ushort* __restrict__ WT,
                                                   int K, int N) {
  __shared__ ushort tile[32][33];
  int n0 = blockIdx.x * 32, k0 = blockIdx.y * 32;
  int tx = threadIdx.x & 31, ty = threadIdx.x >> 5;
#pragma unroll
  for (int i = 0; i < 4; ++i) {
    int k = ty + i * 8;
    tile[tx][k] = f2b(W[(size_t)(k0 + k) * N + n0 + tx]);
  }
  __syncthreads();
#pragma unroll
  for (int i = 0; i < 4; ++i) {
    int nn = ty + i * 8;
    WT[(size_t)(n0 + nn) * K + k0 + tx] = tile[nn][tx];
  }
}

// ---------------------------------------------------------------------------
// LayerNorm: one wave per row of 512, output bf16
// ---------------------------------------------------------------------------
__global__ __launch_bounds__(256) void ln_kernel(const float* __restrict__ x,
                                                 const float* __restrict__ gamma,
                                                 const float* __restrict__ beta,
                                                 ushort* __restrict__ xn) {
  int wid = threadIdx.x >> 6, lane = threadIdx.x & 63;
  int row = blockIdx.x * 4 + wid;
  const float4* xr = (const float4*)(x + (size_t)row * D_MODEL);
  float4 v0 = xr[lane];
  float4 v1 = xr[lane + 64];
  float s = v0.x + v0.y + v0.z + v0.w + v1.x + v1.y + v1.z + v1.w;
  float q = v0.x * v0.x + v0.y * v0.y + v0.z * v0.z + v0.w * v0.w +
            v1.x * v1.x + v1.y * v1.y + v1.z * v1.z + v1.w * v1.w;
#pragma unroll
  for (int m = 1; m < 64; m <<= 1) {
    s += __shfl_xor(s, m, 64);
    q += __shfl_xor(q, m, 64);
  }
  float mu = s * (1.f / 512.f);
  float var = q * (1.f / 512.f) - mu * mu;
  float rs = rsqrtf(var + 1e-5f);
  const float4* g4 = (const float4*)gamma;
  const float4* b4 = (const float4*)beta;
  ushort* out = xn + (size_t)row * D_MODEL;
#pragma unroll
  for (int i = 0; i < 2; ++i) {
    float4 v = i ? v1 : v0;
    float4 gg = g4[lane + i * 64];
    float4 bb = b4[lane + i * 64];
    ushort4 o;
    o.x = f2b((v.x - mu) * rs * gg.x + bb.x);
    o.y = f2b((v.y - mu) * rs * gg.y + bb.y);
    o.z = f2b((v.z - mu) * rs * gg.z + bb.z);
    o.w = f2b((v.w - mu) * rs * gg.w + bb.w);
    *(ushort4*)(out + (lane + i * 64) * 4) = o;
  }
}

// ---------------------------------------------------------------------------
// Fused Q+KV projection GEMM (m97 structure).
// ---------------------------------------------------------------------------
__global__ __launch_bounds__(256) void qkv_gemm(
    const ushort* __restrict__ A, const ushort* __restrict__ BT,
    const float* __restrict__ bq, const float* __restrict__ bkv,
    ushort* __restrict__ qbuf, ushort* __restrict__ kvbuf, float qscale) {
  __shared__ __align__(16) ushort As[128 * 32];
  __shared__ __align__(16) ushort Bs[128 * 32];
  const int tid = threadIdx.x, lane = tid & 63, wid = tid >> 6;
  const int g = lane >> 4, r = lane & 15;
  const int wr = wid >> 1, wc = wid & 1;
  const int bm = blockIdx.y * 128, bn = blockIdx.x * 128;

  f32x4 acc[4][4];
#pragma unroll
  for (int a = 0; a < 4; ++a)
#pragma unroll
    for (int b = 0; b < 4; ++b) acc[a][b] = (f32x4){0.f, 0.f, 0.f, 0.f};

  const int srow = 32 * wid + (lane >> 2);
  const int scol = (lane & 3) * 8;
  const ushort* ga = A + (size_t)(bm + srow) * 512 + scol;
  const ushort* gb = BT + (size_t)(bn + srow) * 512 + scol;
  ushort* la = As + 32 * 32 * wid;
  ushort* lb = Bs + 32 * 32 * wid;

  for (int kb = 0; kb < 512; kb += 32) {
    __syncthreads();
    GLOAD_LDS16(ga + kb, la);
    GLOAD_LDS16(ga + kb + 16 * 512, la + 16 * 32);
    GLOAD_LDS16(gb + kb, lb);
    GLOAD_LDS16(gb + kb + 16 * 512, lb + 16 * 32);
    __syncthreads();
    short8 af[4], bf[4];
#pragma unroll
    for (int i2 = 0; i2 < 4; ++i2) {
      af[i2] = *(const short8*)&As[(wr * 64 + i2 * 16 + r) * 32 + g * 8];
      bf[i2] = *(const short8*)&Bs[(wc * 64 + i2 * 16 + r) * 32 + g * 8];
    }
#pragma unroll
    for (int a = 0; a < 4; ++a)
#pragma unroll
      for (int b = 0; b < 4; ++b) acc[a][b] = mfma16(af[a], bf[b], acc[a][b]);
  }

  const bool isQ = (bn < 512);
  const float* bias = isQ ? bq : bkv;
  ushort* dst = isQ ? qbuf : kvbuf;
  const int cb = isQ ? bn : bn - 512;
  const size_t stride = isQ ? 512 : 1024;
  const float scale = isQ ? qscale : 1.0f;

#pragma unroll
  for (int a = 0; a < 4; ++a) {
#pragma unroll
    for (int reg = 0; reg < 4; ++reg) {
      int row = bm + wr * 64 + a * 16 + g * 4 + reg;
#pragma unroll
      for (int b = 0; b < 4; ++b) {
        int col = cb + wc * 64 + b * 16 + r;
        dst[(size_t)row * stride + col] = f2b((acc[a][b][reg] + bias[col]) * scale);
      }
    }
  }
}

// ---------------------------------------------------------------------------
// Output-projection GEMM (m97 structure), fp32 out with residual.
// ---------------------------------------------------------------------------
__global__ __launch_bounds__(256) void o_gemm(
    const ushort* __restrict__ A, const ushort* __restrict__ BT,
    const float* __restrict__ bias, const float* __restrict__ resid,
    float* __restrict__ outF) {
  __shared__ __align__(16) ushort As[128 * 32];
  __shared__ __align__(16) ushort Bs[128 * 32];
  const int tid = threadIdx.x, lane = tid & 63, wid = tid >> 6;
  const int g = lane >> 4, r = lane & 15;
  const int wr = wid >> 1, wc = wid & 1;
  const int bm = blockIdx.y * 128, bn = blockIdx.x * 128;

  f32x4 acc[4][4];
#pragma unroll
  for (int a = 0; a < 4; ++a)
#pragma unroll
    for (int b = 0; b < 4; ++b) acc[a][b] = (f32x4){0.f, 0.f, 0.f, 0.f};

  const int srow = 32 * wid + (lane >> 2);
  const int scol = (lane & 3) * 8;
  const ushort* ga = A + (size_t)(bm + srow) * 512 + scol;
  const ushort* gb = BT + (size_t)(bn + srow) * 512 + scol;
  ushort* la = As + 32 * 32 * wid;
  ushort* lb = Bs + 32 * 32 * wid;

  for (int kb = 0; kb < 512; kb += 32) {
    __syncthreads();
    GLOAD_LDS16(ga + kb, la);
    GLOAD_LDS16(ga + kb + 16 * 512, la + 16 * 32);
    GLOAD_LDS16(gb + kb, lb);
    GLOAD_LDS16(gb + kb + 16 * 512, lb + 16 * 32);
    __syncthreads();
    short8 af[4], bf[4];
#pragma unroll
    for (int i2 = 0; i2 < 4; ++i2) {
      af[i2] = *(const short8*)&As[(wr * 64 + i2 * 16 + r) * 32 + g * 8];
      bf[i2] = *(const short8*)&Bs[(wc * 64 + i2 * 16 + r) * 32 + g * 8];
    }
#pragma unroll
    for (int a = 0; a < 4; ++a)
#pragma unroll
      for (int b = 0; b < 4; ++b) acc[a][b] = mfma16(af[a], bf[b], acc[a][b]);
  }

#pragma unroll
  for (int a = 0; a < 4; ++a) {
#pragma unroll
    for (int reg = 0; reg < 4; ++reg) {
      int row = bm + wr * 64 + a * 16 + g * 4 + reg;
#pragma unroll
      for (int b = 0; b < 4; ++b) {
        int col = bn + wc * 64 + b * 16 + r;
        outF[(size_t)row * 512 + col] =
            acc[a][b][reg] + bias[col] + resid[(size_t)row * 512 + col];
      }
    }
  }
}

// ---------------------------------------------------------------------------
// Flash attention, split-K with FUSED combine. R3 core: per (n,h) 72 chunk
// blocks, 4 waves x 32 q-rows, 32-key tiles, depth-2 prefetched reg-staged
// K/V, XCD-balanced swizzle. Epilogue: nch==1 groups (qi 0,1) store straight
// to attout; others store partialO+ml, then last-block-of-group (device
// atomic counter + fences) performs the combine inline (L2-hot readback).
// ---------------------------------------------------------------------------
__global__ __launch_bounds__(256) void attn_kernel(
    const ushort* __restrict__ qbuf, const ushort* __restrict__ kvbuf,
    const int* __restrict__ lengths, ushort* __restrict__ partialO,
    float2* __restrict__ mlbuf, ushort* __restrict__ attout,
    int* __restrict__ ctr) {
  __shared__ __align__(16) ushort smem[9728];
  __shared__ int sOld;
  // Kt buf b: smem + b*2304   ([32][72])
  // Vt buf b: smem + 4608 + b*2560  ([64][40], 16B-unit XOR swizzle)

  const int tid = threadIdx.x, lane = tid & 63, wid = tid >> 6;
  const int l31 = lane & 31, h = lane >> 5;

  // XCD-balanced swizzle: XCD k owns head k of every batch.
  const int bid = blockIdx.x;
  const int xcd = bid & 7;
  const int j = bid >> 3;          // 0..287
  const int grp = j / 72;          // batch index
  const int L = j - grp * 72;      // chunk within (n,h)
  const int nh = (grp << 3) | xcd;
  const int n = nh >> 3, head = nh & 7;
  int qi = 0, c = L;
  while (c >= ((qi + 2) >> 1)) { c -= (qi + 2) >> 1; ++qi; }
  const int T = 4 * qi + 4, nch = (qi + 2) >> 1;
  const int t0 = (c * T) / nch;
  const int t1 = ((c + 1) * T) / nch;
  const int slot = nh * CHUNKS_PER_NH + L;

  const int qb = qi * 128;
  const int len = lengths[n];
  const int q0w = qb + 32 * wid;
  const int q_own = q0w + l31;
  const int nt_w_abs = 4 * qi + wid + 1;  // wave computes tiles t < this
  const int tlen = (len + 31) >> 5;
  int nt = min(t1, tlen) - t0;
  if (nt < 0) nt = 0;

  f32x16 o0, o1;
#pragma unroll
  for (int i = 0; i < 16; ++i) { o0[i] = 0.f; o1[i] = 0.f; }
  float m_ = -1e30f, ls = 0.f;

  const int skey = tid >> 3, sc8 = tid & 7;               // K staging
  const int kp = lane & 15, dvb = wid * 4 + (lane >> 4);  // V staging
  const int mu = (l31 >> 2) & 3;                          // V-unit swizzle key

  int voff[4];
#pragma unroll
  for (int jj = 0; jj < 4; ++jj) {
    int dv = 4 * dvb + jj;
    voff[jj] = dv * 20 + (((kp >> 2) ^ ((dv >> 2) & 3)) << 2) + (kp & 3);
  }

  const ushort* kvbase = kvbuf + (size_t)n * SQ * 1024 + head * 64;
  const ushort* kSrc = kvbase + (size_t)(t0 * 32 + skey) * 1024 + sc8 * 8;
  const ushort* vSrc = kvbase + 512 + (size_t)(t0 * 32 + 2 * kp) * 1024 + dvb * 4;
  const int kLdsOff = skey * 72 + sc8 * 8;

  if (nt > 0) {
    // Q fragments (persistent): B-frag col=q=l31, k = 16kc + 8h + e
    short8 qf[4];
    {
      const ushort* qp = qbuf + (size_t)(n * SQ + q_own) * 512 + head * 64 + 8 * h;
#pragma unroll
      for (int kc = 0; kc < 4; ++kc) qf[kc] = *(const short8*)(qp + 16 * kc);
    }

    // two register staging sets; tile t lives in set (t-t0)&1
    uint4 kA, kB = {};
    uint2 vaA, vbA, vaB = {}, vbB = {};
    kA = *(const uint4*)kSrc;
    vaA = *(const uint2*)vSrc;
    vbA = *(const uint2*)(vSrc + 1024);
    kSrc += 32 * 1024;
    vSrc += 32 * 1024;
    if (nt > 1) {
      kB = *(const uint4*)kSrc;
      vaB = *(const uint2*)vSrc;
      vbB = *(const uint2*)(vSrc + 1024);
      kSrc += 32 * 1024;
      vSrc += 32 * 1024;
    }
    {  // write tile 0 (set A) into buffer 0
      *(uint4*)(smem + kLdsOff) = kA;
      const ushort* a16 = (const ushort*)&vaA;
      const ushort* b16 = (const ushort*)&vbA;
#pragma unroll
      for (int jj = 0; jj < 4; ++jj)
        ((unsigned*)(smem + 4608))[voff[jj]] =
            (unsigned)a16[jj] | ((unsigned)b16[jj] << 16);
    }
    __syncthreads();

    for (int i = 0; i < nt; ++i) {
      const int t = t0 + i;
      const int cur = i & 1;
      if (i + 2 < nt) {  // issue loads 2 tiles ahead into the freed set
        if (cur == 0) {
          kA = *(const uint4*)kSrc;
          vaA = *(const uint2*)vSrc;
          vbA = *(const uint2*)(vSrc + 1024);
        } else {
          kB = *(const uint4*)kSrc;
          vaB = *(const uint2*)vSrc;
          vbB = *(const uint2*)(vSrc + 1024);
        }
        kSrc += 32 * 1024;
        vSrc += 32 * 1024;
      }

      if (t < nt_w_abs) {
        const int kb = t * 32;
        const ushort* KtB = smem + cur * 2304;
        const ushort* VtB = smem + 4608 + cur * 2560;

        // QK^T swapped: S^T[key][q], col=q=l31, key(reg)=(reg&3)+8*(reg>>2)+4h
        f32x16 s;
#pragma unroll
        for (int i2 = 0; i2 < 16; ++i2) s[i2] = 0.f;
        {
          const ushort* kr_ = KtB + l31 * 72 + 8 * h;
          short8 k0 = *(const short8*)(kr_);
          short8 k1 = *(const short8*)(kr_ + 16);
          short8 k2 = *(const short8*)(kr_ + 32);
          short8 k3 = *(const short8*)(kr_ + 48);
          __builtin_amdgcn_s_setprio(1);
          s = mfma32(k0, qf[0], s);
          s = mfma32(k1, qf[1], s);
          s = mfma32(k2, qf[2], s);
          s = mfma32(k3, qf[3], s);
          __builtin_amdgcn_s_setprio(0);
        }

        // boundary tiles only: causal + length mask
        if (kb + 31 > q0w || kb + 31 >= len) {
          int keyb = kb + 4 * h;
#pragma unroll
          for (int reg = 0; reg < 16; ++reg) {
            int key = keyb + (reg & 3) + 8 * (reg >> 2);
            bool ok = (key <= q_own) && (key < len);
            s[reg] = ok ? s[reg] : -1e30f;
          }
        }

        // max-reduce as v_max3-fusable tree
        float a0 = fmaxf(fmaxf(s[0], s[1]), s[2]);
        float a1 = fmaxf(fmaxf(s[3], s[4]), s[5]);
        float a2 = fmaxf(fmaxf(s[6], s[7]), s[8]);
        float a3 = fmaxf(fmaxf(s[9], s[10]), s[11]);
        float a4 = fmaxf(fmaxf(s[12], s[13]), s[14]);
        float mx = fmaxf(fmaxf(fmaxf(a0, a1), s[15]),
                         fmaxf(fmaxf(a2, a3), a4));
        {
          auto rr = __builtin_amdgcn_permlane32_swap(__float_as_uint(mx),
                                                     __float_as_uint(mx), false, false);
          mx = fmaxf(__uint_as_float(((const unsigned*)&rr)[0]),
                     __uint_as_float(((const unsigned*)&rr)[1]));
        }

        if (!__all(mx <= m_ + 8.0f)) {
          float mn = fmaxf(m_, mx);
          float sf = __builtin_amdgcn_exp2f(m_ - mn);
          m_ = mn;
          ls *= sf;
#pragma unroll
          for (int i2 = 0; i2 < 16; ++i2) { o0[i2] *= sf; o1[i2] *= sf; }
        }

        float p[16];
#pragma unroll
        for (int reg = 0; reg < 16; ++reg)
          p[reg] = __builtin_amdgcn_exp2f(s[reg] - m_);

        float rsum = ((p[0] + p[1]) + (p[2] + p[3])) + ((p[4] + p[5]) + (p[6] + p[7])) +
                     ((p[8] + p[9]) + (p[10] + p[11])) +
                     ((p[12] + p[13]) + (p[14] + p[15]));
        {
          auto rr = __builtin_amdgcn_permlane32_swap(__float_as_uint(rsum),
                                                     __float_as_uint(rsum), false, false);
          rsum = __uint_as_float(((const unsigned*)&rr)[0]) +
                 __uint_as_float(((const unsigned*)&rr)[1]);
        }
        ls += rsum;

        unsigned pk[8];
#pragma unroll
        for (int jj = 0; jj < 8; ++jj)
          pk[jj] = __builtin_amdgcn_perm(__float_as_uint(p[2 * jj + 1]),
                                         __float_as_uint(p[2 * jj]), 0x07060302u);

        // PV: B-frag = own pk words (k-slot sigma(h,e)=16kc+4h+(e&3)+8(e>>2))
        __builtin_amdgcn_s_setprio(1);
#pragma unroll
        for (int kc = 0; kc < 2; ++kc) {
          short8 pf;
          ((unsigned*)&pf)[0] = pk[4 * kc + 0];
          ((unsigned*)&pf)[1] = pk[4 * kc + 1];
          ((unsigned*)&pf)[2] = pk[4 * kc + 2];
          ((unsigned*)&pf)[3] = pk[4 * kc + 3];
          const int u0 = ((2 * kc) ^ mu) << 3;
          const ushort* vb0 = VtB + l31 * 40 + 4 * h;
          const ushort* vb1 = VtB + (32 + l31) * 40 + 4 * h;
          short8 vf0, vf1;
          ((uint2*)&vf0)[0] = *(const uint2*)(vb0 + u0);
          ((uint2*)&vf0)[1] = *(const uint2*)(vb0 + (u0 ^ 8));
          ((uint2*)&vf1)[0] = *(const uint2*)(vb1 + u0);
          ((uint2*)&vf1)[1] = *(const uint2*)(vb1 + (u0 ^ 8));
          o0 = mfma32(vf0, pf, o0);
          o1 = mfma32(vf1, pf, o1);
        }
        __builtin_amdgcn_s_setprio(0);
      }

      if (i + 1 < nt) {  // write tile i+1's regs (in flight ~1 iteration)
        ushort* KtN = smem + (cur ^ 1) * 2304;
        unsigned* VtN = (unsigned*)(smem + 4608 + (cur ^ 1) * 2560);
        if (cur == 0) {
          *(uint4*)(KtN + kLdsOff) = kB;
          const ushort* a16 = (const ushort*)&vaB;
          const ushort* b16 = (const ushort*)&vbB;
#pragma unroll
          for (int jj = 0; jj < 4; ++jj)
            VtN[voff[jj]] = (unsigned)a16[jj] | ((unsigned)b16[jj] << 16);
        } else {
          *(uint4*)(KtN + kLdsOff) = kA;
          const ushort* a16 = (const ushort*)&vaA;
          const ushort* b16 = (const ushort*)&vbA;
#pragma unroll
          for (int jj = 0; jj < 4; ++jj)
            VtN[voff[jj]] = (unsigned)a16[jj] | ((unsigned)b16[jj] << 16);
        }
      }
      __syncthreads();
    }
  }

  // ---- epilogue: normalize partial, transpose via LDS ----
  const unsigned long long alive = __ballot(ls > 0.f);
  {
    float inv = (ls > 0.f) ? 1.f / ls : 0.f;
    ushort* OtW = smem + wid * (32 * 68);
#pragma unroll
    for (int b = 0; b < 2; ++b) {
#pragma unroll
      for (int reg = 0; reg < 16; reg += 2) {
        float e0 = (b ? o1[reg] : o0[reg]) * inv;
        float e1 = (b ? o1[reg + 1] : o0[reg + 1]) * inv;
        unsigned pko = __builtin_amdgcn_perm(__float_as_uint(e1),
                                             __float_as_uint(e0), 0x07060302u);
        int dv = 32 * b + (reg & 3) + 8 * (reg >> 2) + 4 * h;
        *(unsigned*)(OtW + l31 * 68 + dv) = pko;
      }
    }
    if (h == 0 && nch > 1)
      mlbuf[slot * 128 + 32 * wid + l31] = make_float2(m_, ls);
  }
  __syncthreads();

  if (nch == 1) {
    // qi 0/1: single chunk covers keys [0, T*32) -> every row live (key 0
    // always valid). Write normalized O straight to attout; no combine.
    int r = lane >> 1, sg = lane & 1;
    const ushort* rp = smem + wid * (32 * 68) + r * 68 + sg * 32;
    uint2 d0 = *(const uint2*)(rp);
    uint2 d1 = *(const uint2*)(rp + 4);
    uint2 d2 = *(const uint2*)(rp + 8);
    uint2 d3 = *(const uint2*)(rp + 12);
    uint2 d4 = *(const uint2*)(rp + 16);
    uint2 d5 = *(const uint2*)(rp + 20);
    uint2 d6 = *(const uint2*)(rp + 24);
    uint2 d7 = *(const uint2*)(rp + 28);
    ushort* gp = attout + (size_t)(n * SQ + qb + 32 * wid + r) * 512 +
                 head * 64 + sg * 32;
    *(uint4*)(gp) = make_uint4(d0.x, d0.y, d1.x, d1.y);
    *(uint4*)(gp + 8) = make_uint4(d2.x, d2.y, d3.x, d3.y);
    *(uint4*)(gp + 16) = make_uint4(d4.x, d4.y, d5.x, d5.y);
    *(uint4*)(gp + 24) = make_uint4(d6.x, d6.y, d7.x, d7.y);
    return;
  }

  // multi-chunk: store partialO rows that are alive
  if (alive) {
    int r = lane >> 1, sg = lane & 1;
    if ((alive >> r) & 1ULL) {
      const ushort* rp = smem + wid * (32 * 68) + r * 68 + sg * 32;
      uint2 d0 = *(const uint2*)(rp);
      uint2 d1 = *(const uint2*)(rp + 4);
      uint2 d2 = *(const uint2*)(rp + 8);
      uint2 d3 = *(const uint2*)(rp + 12);
      uint2 d4 = *(const uint2*)(rp + 16);
      uint2 d5 = *(const uint2*)(rp + 20);
      uint2 d6 = *(const uint2*)(rp + 24);
      uint2 d7 = *(const uint2*)(rp + 28);
      ushort* gp = partialO + (size_t)slot * 8192 + (32 * wid + r) * 64 + sg * 32;
      *(uint4*)(gp) = make_uint4(d0.x, d0.y, d1.x, d1.y);
      *(uint4*)(gp + 8) = make_uint4(d2.x, d2.y, d3.x, d3.y);
      *(uint4*)(gp + 16) = make_uint4(d4.x, d4.y, d5.x, d5.y);
      *(uint4*)(gp + 24) = make_uint4(d6.x, d6.y, d7.x, d7.y);
    }
  }

  // last-block-of-group does the combine (release/acquire via threadfence)
  __syncthreads();
  if (tid == 0) {
    __threadfence();  // make this block's partialO/mlbuf visible device-wide
    sOld = atomicAdd(&ctr[nh * 16 + qi], 1);
  }
  __syncthreads();
  if (sOld != nch - 1) return;
  __threadfence();  // acquire: observe other blocks' partials

  {
    const int slot0 = slot - c;
    const int r = tid >> 1, half = tid & 1;
    float mstar = -1e30f;
    for (int cc = 0; cc < nch; ++cc)
      mstar = fmaxf(mstar, mlbuf[(slot0 + cc) * 128 + r].x);

    ushort* gp = attout + (size_t)(n * SQ + qi * 128 + r) * 512 +
                 head * 64 + half * 32;
#pragma unroll
    for (int pass = 0; pass < 2; ++pass) {
      float acc[16];
#pragma unroll
      for (int k = 0; k < 16; ++k) acc[k] = 0.f;
      float Lsum = 0.f;
      for (int cc = 0; cc < nch; ++cc) {
        float2 ml = mlbuf[(slot0 + cc) * 128 + r];
        if (ml.y > 0.f) {
          float cf = ml.y * __builtin_amdgcn_exp2f(ml.x - mstar);
          Lsum += cf;
          const uint4* p = (const uint4*)(partialO + (size_t)(slot0 + cc) * 8192 +
                                          r * 64 + half * 32 + pass * 16);
#pragma unroll
          for (int u = 0; u < 2; ++u) {
            uint4 d = p[u];
            unsigned w[4] = {d.x, d.y, d.z, d.w};
#pragma unroll
            for (int k = 0; k < 4; ++k) {
              acc[u * 8 + 2 * k] += cf * __uint_as_float(w[k] << 16);
              acc[u * 8 + 2 * k + 1] += cf * __uint_as_float(w[k] & 0xffff0000u);
            }
          }
        }
      }
      const float inv = 1.f / Lsum;
      ushort* gpp = gp + pass * 16;
#pragma unroll
      for (int u = 0; u < 2; ++u) {
        unsigned ww[4];
#pragma unroll
        for (int k = 0; k < 4; ++k) {
          float e0 = acc[u * 8 + 2 * k] * inv;
          float e1 = acc[u * 8 + 2 * k + 1] * inv;
          ww[k] = ((unsigned)f2b(e0)) | (((unsigned)f2b(e1)) << 16);
        }
        ((uint4*)gpp)[u] = make_uint4(ww[0], ww[1], ww[2], ww[3]);
      }
    }
  }
}

// ---------------------------------------------------------------------------
extern "C" void kernel_launch(void* const* d_in, const int* in_sizes, int n_in,
                              void* d_out, int out_size, void* d_ws, size_t ws_size,
                              hipStream_t stream) {
  const float* x = (const float*)d_in[0];
  const int* lens = (const int*)d_in[1];
  const float* Wq = (const float*)d_in[2];
  const float* bq = (const float*)d_in[3];
  const float* Wkv = (const float*)d_in[4];
  const float* bkv = (const float*)d_in[5];
  const float* Wo = (const float*)d_in[6];
  const float* bo = (const float*)d_in[7];
  const float* gamma = (const float*)d_in[8];
  const float* beta = (const float*)d_in[9];
  float* out = (float*)d_out;

  size_t off = 0;
  auto alloc = [&](size_t bytes) {
    void* p = (char*)d_ws + off;
    off += (bytes + 255) & ~(size_t)255;
    return p;
  };
  ushort* xn = (ushort*)alloc((size_t)MROWS * 512 * 2);
  ushort* qbuf = (ushort*)alloc((size_t)MROWS * 512 * 2);
  ushort* kvbuf = (ushort*)alloc((size_t)MROWS * 1024 * 2);
  ushort* WT = (ushort*)alloc((size_t)1536 * 512 * 2);  // [Wq^T ; Wkv^T]
  ushort* WoT = (ushort*)alloc((size_t)512 * 512 * 2);
  ushort* partialO = (ushort*)alloc((size_t)NSLOTS * 8192 * 2);  // 37.7 MB
  float2* mlbuf = (float2*)alloc((size_t)NSLOTS * 128 * 8);      // 2.4 MB
  int* ctr = (int*)alloc(512 * sizeof(int));
  ushort* attout = xn;  // xn dead after the QKV GEMM (stream-ordered)

  hipMemsetAsync(ctr, 0, 512 * sizeof(int), stream);

  transpose_w<<<dim3(16, 16), 256, 0, stream>>>(Wq, WT, 512, 512);
  transpose_w<<<dim3(32, 16), 256, 0, stream>>>(Wkv, WT + 512 * 512, 512, 1024);
  transpose_w<<<dim3(16, 16), 256, 0, stream>>>(Wo, WoT, 512, 512);

  ln_kernel<<<MROWS / 4, 256, 0, stream>>>(x, gamma, beta, xn);

  // Q pre-scaled by 1/sqrt(dq) * log2(e) so attention uses exp2 directly
  qkv_gemm<<<dim3(12, 64), 256, 0, stream>>>(xn, WT, bq, bkv, qbuf, kvbuf,
                                             0.125f * 1.44269504f);

  attn_kernel<<<dim3(NSLOTS), 256, 0, stream>>>(qbuf, kvbuf, lens, partialO,
                                                mlbuf, attout, ctr);

  o_gemm<<<dim3(4, 64), 256, 0, stream>>>(attout, WoT, bo, x, out);
}

// Round 8
// 119.294 us; speedup vs baseline: 2.2398x; 2.2398x over previous
//
#include <hip/hip_runtime.h>
#include <hip/hip_bf16.h>

typedef __attribute__((ext_vector_type(4))) float f32x4;
typedef __attribute__((ext_vector_type(16))) float f32x16;
typedef __attribute__((ext_vector_type(8))) short short8;

#define D_MODEL 512
#define SQ 2048
#define NH 8
#define NBATCH 4
#define MROWS (NBATCH * SQ)  // 8192

// split-K chunking: per qi (0..15), T=4*qi+4 tiles split into nch=(qi+2)>>1
// balanced chunks (sizes 4..8). Blocks per (n,h) = sum nch = 72.
#define CHUNKS_PER_NH 72
#define NSLOTS (32 * CHUNKS_PER_NH)  // 2304

__device__ __forceinline__ ushort f2b(float x) {
  unsigned int u = __float_as_uint(x);
  return (ushort)((u + 0x7fffu + ((u >> 16) & 1u)) >> 16);
}

__device__ __forceinline__ f32x4 mfma16(short8 a, short8 b, f32x4 c) {
  return __builtin_amdgcn_mfma_f32_16x16x32_bf16(a, b, c, 0, 0, 0);
}
__device__ __forceinline__ f32x16 mfma32(short8 a, short8 b, f32x16 c) {
  return __builtin_amdgcn_mfma_f32_32x32x16_bf16(a, b, c, 0, 0, 0);
}

#define GLOAD_LDS16(g, l)                                                      \
  __builtin_amdgcn_global_load_lds(                                            \
      (const __attribute__((address_space(1))) unsigned int*)(g),              \
      (__attribute__((address_space(3))) unsigned int*)(l), 16, 0, 0)

// ---------------------------------------------------------------------------
// Batched weight transpose + fp32 -> bf16 cast (Wq, Wkv, Wo in ONE launch).
// Tile map: blocks [0,256) Wq(512x512), [256,768) Wkv(512x1024),
// [768,1024) Wo(512x512). All have K=512 rows.
// ---------------------------------------------------------------------------
__global__ __launch_bounds__(256) void transpose_all(
    const float* __restrict__ Wq, const float* __restrict__ Wkv,
    const float* __restrict__ Wo, ushort* __restrict__ WT,
    ushort* __restrict__ WoT) {
  __shared__ ushort tile[32][33];
  int b = blockIdx.x;
  const float* W;
  ushort* D;
  int N;
  if (b < 256) {
    W = Wq; D = WT; N = 512;
  } else if (b < 768) {
    W = Wkv; D = WT + 512 * 512; N = 1024; b -= 256;
  } else {
    W = Wo; D = WoT; N = 512; b -= 768;
  }
  const int ntx = N >> 5;
  int n0 = (b % ntx) * 32, k0 = (b / ntx) * 32;
  int tx = threadIdx.x & 31, ty = threadIdx.x >> 5;
#pragma unroll
  for (int i = 0; i < 4; ++i) {
    int k = ty + i * 8;
    tile[tx][k] = f2b(W[(size_t)(k0 + k) * N + n0 + tx]);
  }
  __syncthreads();
#pragma unroll
  for (int i = 0; i < 4; ++i) {
    int nn = ty + i * 8;
    D[(size_t)(n0 + nn) * 512 + k0 + tx] = tile[nn][tx];
  }
}

// ---------------------------------------------------------------------------
// LayerNorm: one wave per row of 512, output bf16
// ---------------------------------------------------------------------------
__global__ __launch_bounds__(256) void ln_kernel(const float* __restrict__ x,
                                                 const float* __restrict__ gamma,
                                                 const float* __restrict__ beta,
                                                 ushort* __restrict__ xn) {
  int wid = threadIdx.x >> 6, lane = threadIdx.x & 63;
  int row = blockIdx.x * 4 + wid;
  const float4* xr = (const float4*)(x + (size_t)row * D_MODEL);
  float4 v0 = xr[lane];
  float4 v1 = xr[lane + 64];
  float s = v0.x + v0.y + v0.z + v0.w + v1.x + v1.y + v1.z + v1.w;
  float q = v0.x * v0.x + v0.y * v0.y + v0.z * v0.z + v0.w * v0.w +
            v1.x * v1.x + v1.y * v1.y + v1.z * v1.z + v1.w * v1.w;
#pragma unroll
  for (int m = 1; m < 64; m <<= 1) {
    s += __shfl_xor(s, m, 64);
    q += __shfl_xor(q, m, 64);
  }
  float mu = s * (1.f / 512.f);
  float var = q * (1.f / 512.f) - mu * mu;
  float rs = rsqrtf(var + 1e-5f);
  const float4* g4 = (const float4*)gamma;
  const float4* b4 = (const float4*)beta;
  ushort* out = xn + (size_t)row * D_MODEL;
#pragma unroll
  for (int i = 0; i < 2; ++i) {
    float4 v = i ? v1 : v0;
    float4 gg = g4[lane + i * 64];
    float4 bb = b4[lane + i * 64];
    ushort4 o;
    o.x = f2b((v.x - mu) * rs * gg.x + bb.x);
    o.y = f2b((v.y - mu) * rs * gg.y + bb.y);
    o.z = f2b((v.z - mu) * rs * gg.z + bb.z);
    o.w = f2b((v.w - mu) * rs * gg.w + bb.w);
    *(ushort4*)(out + (lane + i * 64) * 4) = o;
  }
}

// ---------------------------------------------------------------------------
// Fused Q+KV projection GEMM (m97 structure).
// ---------------------------------------------------------------------------
__global__ __launch_bounds__(256) void qkv_gemm(
    const ushort* __restrict__ A, const ushort* __restrict__ BT,
    const float* __restrict__ bq, const float* __restrict__ bkv,
    ushort* __restrict__ qbuf, ushort* __restrict__ kvbuf, float qscale) {
  __shared__ __align__(16) ushort As[128 * 32];
  __shared__ __align__(16) ushort Bs[128 * 32];
  const int tid = threadIdx.x, lane = tid & 63, wid = tid >> 6;
  const int g = lane >> 4, r = lane & 15;
  const int wr = wid >> 1, wc = wid & 1;
  const int bm = blockIdx.y * 128, bn = blockIdx.x * 128;

  f32x4 acc[4][4];
#pragma unroll
  for (int a = 0; a < 4; ++a)
#pragma unroll
    for (int b = 0; b < 4; ++b) acc[a][b] = (f32x4){0.f, 0.f, 0.f, 0.f};

  const int srow = 32 * wid + (lane >> 2);
  const int scol = (lane & 3) * 8;
  const ushort* ga = A + (size_t)(bm + srow) * 512 + scol;
  const ushort* gb = BT + (size_t)(bn + srow) * 512 + scol;
  ushort* la = As + 32 * 32 * wid;
  ushort* lb = Bs + 32 * 32 * wid;

  for (int kb = 0; kb < 512; kb += 32) {
    __syncthreads();
    GLOAD_LDS16(ga + kb, la);
    GLOAD_LDS16(ga + kb + 16 * 512, la + 16 * 32);
    GLOAD_LDS16(gb + kb, lb);
    GLOAD_LDS16(gb + kb + 16 * 512, lb + 16 * 32);
    __syncthreads();
    short8 af[4], bf[4];
#pragma unroll
    for (int i2 = 0; i2 < 4; ++i2) {
      af[i2] = *(const short8*)&As[(wr * 64 + i2 * 16 + r) * 32 + g * 8];
      bf[i2] = *(const short8*)&Bs[(wc * 64 + i2 * 16 + r) * 32 + g * 8];
    }
#pragma unroll
    for (int a = 0; a < 4; ++a)
#pragma unroll
      for (int b = 0; b < 4; ++b) acc[a][b] = mfma16(af[a], bf[b], acc[a][b]);
  }

  const bool isQ = (bn < 512);
  const float* bias = isQ ? bq : bkv;
  ushort* dst = isQ ? qbuf : kvbuf;
  const int cb = isQ ? bn : bn - 512;
  const size_t stride = isQ ? 512 : 1024;
  const float scale = isQ ? qscale : 1.0f;

#pragma unroll
  for (int a = 0; a < 4; ++a) {
#pragma unroll
    for (int reg = 0; reg < 4; ++reg) {
      int row = bm + wr * 64 + a * 16 + g * 4 + reg;
#pragma unroll
      for (int b = 0; b < 4; ++b) {
        int col = cb + wc * 64 + b * 16 + r;
        dst[(size_t)row * stride + col] = f2b((acc[a][b][reg] + bias[col]) * scale);
      }
    }
  }
}

// ---------------------------------------------------------------------------
// Output-projection GEMM (m97 structure), fp32 out with residual.
// ---------------------------------------------------------------------------
__global__ __launch_bounds__(256) void o_gemm(
    const ushort* __restrict__ A, const ushort* __restrict__ BT,
    const float* __restrict__ bias, const float* __restrict__ resid,
    float* __restrict__ outF) {
  __shared__ __align__(16) ushort As[128 * 32];
  __shared__ __align__(16) ushort Bs[128 * 32];
  const int tid = threadIdx.x, lane = tid & 63, wid = tid >> 6;
  const int g = lane >> 4, r = lane & 15;
  const int wr = wid >> 1, wc = wid & 1;
  const int bm = blockIdx.y * 128, bn = blockIdx.x * 128;

  f32x4 acc[4][4];
#pragma unroll
  for (int a = 0; a < 4; ++a)
#pragma unroll
    for (int b = 0; b < 4; ++b) acc[a][b] = (f32x4){0.f, 0.f, 0.f, 0.f};

  const int srow = 32 * wid + (lane >> 2);
  const int scol = (lane & 3) * 8;
  const ushort* ga = A + (size_t)(bm + srow) * 512 + scol;
  const ushort* gb = BT + (size_t)(bn + srow) * 512 + scol;
  ushort* la = As + 32 * 32 * wid;
  ushort* lb = Bs + 32 * 32 * wid;

  for (int kb = 0; kb < 512; kb += 32) {
    __syncthreads();
    GLOAD_LDS16(ga + kb, la);
    GLOAD_LDS16(ga + kb + 16 * 512, la + 16 * 32);
    GLOAD_LDS16(gb + kb, lb);
    GLOAD_LDS16(gb + kb + 16 * 512, lb + 16 * 32);
    __syncthreads();
    short8 af[4], bf[4];
#pragma unroll
    for (int i2 = 0; i2 < 4; ++i2) {
      af[i2] = *(const short8*)&As[(wr * 64 + i2 * 16 + r) * 32 + g * 8];
      bf[i2] = *(const short8*)&Bs[(wc * 64 + i2 * 16 + r) * 32 + g * 8];
    }
#pragma unroll
    for (int a = 0; a < 4; ++a)
#pragma unroll
      for (int b = 0; b < 4; ++b) acc[a][b] = mfma16(af[a], bf[b], acc[a][b]);
  }

#pragma unroll
  for (int a = 0; a < 4; ++a) {
#pragma unroll
    for (int reg = 0; reg < 4; ++reg) {
      int row = bm + wr * 64 + a * 16 + g * 4 + reg;
#pragma unroll
      for (int b = 0; b < 4; ++b) {
        int col = bn + wc * 64 + b * 16 + r;
        outF[(size_t)row * 512 + col] =
            acc[a][b][reg] + bias[col] + resid[(size_t)row * 512 + col];
      }
    }
  }
}

// ---------------------------------------------------------------------------
// Flash attention, split-K (R3 core). Per (n,h): 72 chunk-blocks; 4 waves x
// 32 q-rows; 32-key tiles; depth-2 prefetched reg-staged K/V; XCD-balanced
// swizzle; LPT dispatch order (longest chunks first: L' = 71-L). nch==1
// groups (qi 0,1) write attout directly (no combine); others write
// partialO + (m,l) for the separate combine kernel.
// ---------------------------------------------------------------------------
__global__ __launch_bounds__(256) void attn_kernel(
    const ushort* __restrict__ qbuf, const ushort* __restrict__ kvbuf,
    const int* __restrict__ lengths, ushort* __restrict__ partialO,
    float2* __restrict__ mlbuf, ushort* __restrict__ attout) {
  __shared__ __align__(16) ushort smem[9728];
  // Kt buf b: smem + b*2304   ([32][72])
  // Vt buf b: smem + 4608 + b*2560  ([64][40], 16B-unit XOR swizzle)

  const int tid = threadIdx.x, lane = tid & 63, wid = tid >> 6;
  const int l31 = lane & 31, h = lane >> 5;

  // XCD-balanced swizzle: XCD k owns head k of every batch. LPT: reverse
  // chunk order so 8-tile chunks (qi=15) dispatch before 4-tile ones.
  const int bid = blockIdx.x;
  const int xcd = bid & 7;
  const int j = bid >> 3;          // 0..287
  const int grp = j / 72;          // batch index
  const int L = 71 - (j - grp * 72);  // chunk within (n,h), reversed
  const int nh = (grp << 3) | xcd;
  const int n = nh >> 3, head = nh & 7;
  int qi = 0, c = L;
  while (c >= ((qi + 2) >> 1)) { c -= (qi + 2) >> 1; ++qi; }
  const int T = 4 * qi + 4, nch = (qi + 2) >> 1;
  const int t0 = (c * T) / nch;
  const int t1 = ((c + 1) * T) / nch;
  const int slot = nh * CHUNKS_PER_NH + L;

  const int qb = qi * 128;
  const int len = lengths[n];
  const int q0w = qb + 32 * wid;
  const int q_own = q0w + l31;
  const int nt_w_abs = 4 * qi + wid + 1;  // wave computes tiles t < this
  const int tlen = (len + 31) >> 5;
  int nt = min(t1, tlen) - t0;
  if (nt < 0) nt = 0;

  f32x16 o0, o1;
#pragma unroll
  for (int i = 0; i < 16; ++i) { o0[i] = 0.f; o1[i] = 0.f; }
  float m_ = -1e30f, ls = 0.f;

  const int skey = tid >> 3, sc8 = tid & 7;               // K staging
  const int kp = lane & 15, dvb = wid * 4 + (lane >> 4);  // V staging
  const int mu = (l31 >> 2) & 3;                          // V-unit swizzle key

  int voff[4];
#pragma unroll
  for (int jj = 0; jj < 4; ++jj) {
    int dv = 4 * dvb + jj;
    voff[jj] = dv * 20 + (((kp >> 2) ^ ((dv >> 2) & 3)) << 2) + (kp & 3);
  }

  const ushort* kvbase = kvbuf + (size_t)n * SQ * 1024 + head * 64;
  const ushort* kSrc = kvbase + (size_t)(t0 * 32 + skey) * 1024 + sc8 * 8;
  const ushort* vSrc = kvbase + 512 + (size_t)(t0 * 32 + 2 * kp) * 1024 + dvb * 4;
  const int kLdsOff = skey * 72 + sc8 * 8;

  if (nt > 0) {
    // Q fragments (persistent): B-frag col=q=l31, k = 16kc + 8h + e
    short8 qf[4];
    {
      const ushort* qp = qbuf + (size_t)(n * SQ + q_own) * 512 + head * 64 + 8 * h;
#pragma unroll
      for (int kc = 0; kc < 4; ++kc) qf[kc] = *(const short8*)(qp + 16 * kc);
    }

    // two register staging sets; tile t lives in set (t-t0)&1
    uint4 kA, kB = {};
    uint2 vaA, vbA, vaB = {}, vbB = {};
    kA = *(const uint4*)kSrc;
    vaA = *(const uint2*)vSrc;
    vbA = *(const uint2*)(vSrc + 1024);
    kSrc += 32 * 1024;
    vSrc += 32 * 1024;
    if (nt > 1) {
      kB = *(const uint4*)kSrc;
      vaB = *(const uint2*)vSrc;
      vbB = *(const uint2*)(vSrc + 1024);
      kSrc += 32 * 1024;
      vSrc += 32 * 1024;
    }
    {  // write tile 0 (set A) into buffer 0
      *(uint4*)(smem + kLdsOff) = kA;
      const ushort* a16 = (const ushort*)&vaA;
      const ushort* b16 = (const ushort*)&vbA;
#pragma unroll
      for (int jj = 0; jj < 4; ++jj)
        ((unsigned*)(smem + 4608))[voff[jj]] =
            (unsigned)a16[jj] | ((unsigned)b16[jj] << 16);
    }
    __syncthreads();

    for (int i = 0; i < nt; ++i) {
      const int t = t0 + i;
      const int cur = i & 1;
      if (i + 2 < nt) {  // issue loads 2 tiles ahead into the freed set
        if (cur == 0) {
          kA = *(const uint4*)kSrc;
          vaA = *(const uint2*)vSrc;
          vbA = *(const uint2*)(vSrc + 1024);
        } else {
          kB = *(const uint4*)kSrc;
          vaB = *(const uint2*)vSrc;
          vbB = *(const uint2*)(vSrc + 1024);
        }
        kSrc += 32 * 1024;
        vSrc += 32 * 1024;
      }

      if (t < nt_w_abs) {
        const int kb = t * 32;
        const ushort* KtB = smem + cur * 2304;
        const ushort* VtB = smem + 4608 + cur * 2560;

        // QK^T swapped: S^T[key][q], col=q=l31, key(reg)=(reg&3)+8*(reg>>2)+4h
        f32x16 s;
#pragma unroll
        for (int i2 = 0; i2 < 16; ++i2) s[i2] = 0.f;
        {
          const ushort* kr_ = KtB + l31 * 72 + 8 * h;
          short8 k0 = *(const short8*)(kr_);
          short8 k1 = *(const short8*)(kr_ + 16);
          short8 k2 = *(const short8*)(kr_ + 32);
          short8 k3 = *(const short8*)(kr_ + 48);
          __builtin_amdgcn_s_setprio(1);
          s = mfma32(k0, qf[0], s);
          s = mfma32(k1, qf[1], s);
          s = mfma32(k2, qf[2], s);
          s = mfma32(k3, qf[3], s);
          __builtin_amdgcn_s_setprio(0);
        }

        // boundary tiles only: causal + length mask
        if (kb + 31 > q0w || kb + 31 >= len) {
          int keyb = kb + 4 * h;
#pragma unroll
          for (int reg = 0; reg < 16; ++reg) {
            int key = keyb + (reg & 3) + 8 * (reg >> 2);
            bool ok = (key <= q_own) && (key < len);
            s[reg] = ok ? s[reg] : -1e30f;
          }
        }

        // max-reduce as v_max3-fusable tree
        float a0 = fmaxf(fmaxf(s[0], s[1]), s[2]);
        float a1 = fmaxf(fmaxf(s[3], s[4]), s[5]);
        float a2 = fmaxf(fmaxf(s[6], s[7]), s[8]);
        float a3 = fmaxf(fmaxf(s[9], s[10]), s[11]);
        float a4 = fmaxf(fmaxf(s[12], s[13]), s[14]);
        float mx = fmaxf(fmaxf(fmaxf(a0, a1), s[15]),
                         fmaxf(fmaxf(a2, a3), a4));
        {
          auto rr = __builtin_amdgcn_permlane32_swap(__float_as_uint(mx),
                                                     __float_as_uint(mx), false, false);
          mx = fmaxf(__uint_as_float(((const unsigned*)&rr)[0]),
                     __uint_as_float(((const unsigned*)&rr)[1]));
        }

        if (!__all(mx <= m_ + 8.0f)) {
          float mn = fmaxf(m_, mx);
          float sf = __builtin_amdgcn_exp2f(m_ - mn);
          m_ = mn;
          ls *= sf;
#pragma unroll
          for (int i2 = 0; i2 < 16; ++i2) { o0[i2] *= sf; o1[i2] *= sf; }
        }

        float p[16];
#pragma unroll
        for (int reg = 0; reg < 16; ++reg)
          p[reg] = __builtin_amdgcn_exp2f(s[reg] - m_);

        float rsum = ((p[0] + p[1]) + (p[2] + p[3])) + ((p[4] + p[5]) + (p[6] + p[7])) +
                     ((p[8] + p[9]) + (p[10] + p[11])) +
                     ((p[12] + p[13]) + (p[14] + p[15]));
        {
          auto rr = __builtin_amdgcn_permlane32_swap(__float_as_uint(rsum),
                                                     __float_as_uint(rsum), false, false);
          rsum = __uint_as_float(((const unsigned*)&rr)[0]) +
                 __uint_as_float(((const unsigned*)&rr)[1]);
        }
        ls += rsum;

        unsigned pk[8];
#pragma unroll
        for (int jj = 0; jj < 8; ++jj)
          pk[jj] = __builtin_amdgcn_perm(__float_as_uint(p[2 * jj + 1]),
                                         __float_as_uint(p[2 * jj]), 0x07060302u);

        // PV: B-frag = own pk words (k-slot sigma(h,e)=16kc+4h+(e&3)+8(e>>2))
        __builtin_amdgcn_s_setprio(1);
#pragma unroll
        for (int kc = 0; kc < 2; ++kc) {
          short8 pf;
          ((unsigned*)&pf)[0] = pk[4 * kc + 0];
          ((unsigned*)&pf)[1] = pk[4 * kc + 1];
          ((unsigned*)&pf)[2] = pk[4 * kc + 2];
          ((unsigned*)&pf)[3] = pk[4 * kc + 3];
          const int u0 = ((2 * kc) ^ mu) << 3;
          const ushort* vb0 = VtB + l31 * 40 + 4 * h;
          const ushort* vb1 = VtB + (32 + l31) * 40 + 4 * h;
          short8 vf0, vf1;
          ((uint2*)&vf0)[0] = *(const uint2*)(vb0 + u0);
          ((uint2*)&vf0)[1] = *(const uint2*)(vb0 + (u0 ^ 8));
          ((uint2*)&vf1)[0] = *(const uint2*)(vb1 + u0);
          ((uint2*)&vf1)[1] = *(const uint2*)(vb1 + (u0 ^ 8));
          o0 = mfma32(vf0, pf, o0);
          o1 = mfma32(vf1, pf, o1);
        }
        __builtin_amdgcn_s_setprio(0);
      }

      if (i + 1 < nt) {  // write tile i+1's regs (in flight ~1 iteration)
        ushort* KtN = smem + (cur ^ 1) * 2304;
        unsigned* VtN = (unsigned*)(smem + 4608 + (cur ^ 1) * 2560);
        if (cur == 0) {
          *(uint4*)(KtN + kLdsOff) = kB;
          const ushort* a16 = (const ushort*)&vaB;
          const ushort* b16 = (const ushort*)&vbB;
#pragma unroll
          for (int jj = 0; jj < 4; ++jj)
            VtN[voff[jj]] = (unsigned)a16[jj] | ((unsigned)b16[jj] << 16);
        } else {
          *(uint4*)(KtN + kLdsOff) = kA;
          const ushort* a16 = (const ushort*)&vaA;
          const ushort* b16 = (const ushort*)&vbA;
#pragma unroll
          for (int jj = 0; jj < 4; ++jj)
            VtN[voff[jj]] = (unsigned)a16[jj] | ((unsigned)b16[jj] << 16);
        }
      }
      __syncthreads();
    }
  }

  // epilogue: normalize partial, transpose via LDS, store.
  const unsigned long long alive = __ballot(ls > 0.f);
  {
    float inv = (ls > 0.f) ? 1.f / ls : 0.f;
    ushort* OtW = smem + wid * (32 * 68);
#pragma unroll
    for (int b = 0; b < 2; ++b) {
#pragma unroll
      for (int reg = 0; reg < 16; reg += 2) {
        float e0 = (b ? o1[reg] : o0[reg]) * inv;
        float e1 = (b ? o1[reg + 1] : o0[reg + 1]) * inv;
        unsigned pko = __builtin_amdgcn_perm(__float_as_uint(e1),
                                             __float_as_uint(e0), 0x07060302u);
        int dv = 32 * b + (reg & 3) + 8 * (reg >> 2) + 4 * h;
        *(unsigned*)(OtW + l31 * 68 + dv) = pko;
      }
    }
    if (h == 0 && nch > 1)
      mlbuf[slot * 128 + 32 * wid + l31] = make_float2(m_, ls);
  }
  __syncthreads();

  if (nch == 1) {
    // qi 0/1: single chunk covers keys from 0; key 0 is causally valid for
    // every q-row and len>=1, so all rows live. Direct store to attout.
    int r = lane >> 1, sg = lane & 1;
    const ushort* rp = smem + wid * (32 * 68) + r * 68 + sg * 32;
    uint2 d0 = *(const uint2*)(rp);
    uint2 d1 = *(const uint2*)(rp + 4);
    uint2 d2 = *(const uint2*)(rp + 8);
    uint2 d3 = *(const uint2*)(rp + 12);
    uint2 d4 = *(const uint2*)(rp + 16);
    uint2 d5 = *(const uint2*)(rp + 20);
    uint2 d6 = *(const uint2*)(rp + 24);
    uint2 d7 = *(const uint2*)(rp + 28);
    ushort* gp = attout + (size_t)(n * SQ + qb + 32 * wid + r) * 512 +
                 head * 64 + sg * 32;
    *(uint4*)(gp) = make_uint4(d0.x, d0.y, d1.x, d1.y);
    *(uint4*)(gp + 8) = make_uint4(d2.x, d2.y, d3.x, d3.y);
    *(uint4*)(gp + 16) = make_uint4(d4.x, d4.y, d5.x, d5.y);
    *(uint4*)(gp + 24) = make_uint4(d6.x, d6.y, d7.x, d7.y);
    return;
  }

  if (alive) {
    int r = lane >> 1, sg = lane & 1;
    if ((alive >> r) & 1ULL) {
      const ushort* rp = smem + wid * (32 * 68) + r * 68 + sg * 32;
      uint2 d0 = *(const uint2*)(rp);
      uint2 d1 = *(const uint2*)(rp + 4);
      uint2 d2 = *(const uint2*)(rp + 8);
      uint2 d3 = *(const uint2*)(rp + 12);
      uint2 d4 = *(const uint2*)(rp + 16);
      uint2 d5 = *(const uint2*)(rp + 20);
      uint2 d6 = *(const uint2*)(rp + 24);
      uint2 d7 = *(const uint2*)(rp + 28);
      ushort* gp = partialO + (size_t)slot * 8192 + (32 * wid + r) * 64 + sg * 32;
      *(uint4*)(gp) = make_uint4(d0.x, d0.y, d1.x, d1.y);
      *(uint4*)(gp + 8) = make_uint4(d2.x, d2.y, d3.x, d3.y);
      *(uint4*)(gp + 16) = make_uint4(d4.x, d4.y, d5.x, d5.y);
      *(uint4*)(gp + 24) = make_uint4(d6.x, d6.y, d7.x, d7.y);
    }
  }
}

// ---------------------------------------------------------------------------
// Split-K combine for qi >= 2 only (nch 2..8): per (n,h,qi), merge partials.
// out = sum_c coef_c * Onorm_c / sum_c coef_c,  coef_c = l_c*exp2(m_c - m*).
// ---------------------------------------------------------------------------
__global__ __launch_bounds__(256) void attn_combine(
    const ushort* __restrict__ partialO, const float2* __restrict__ mlbuf,
    ushort* __restrict__ attout) {
  const int bx = blockIdx.x;  // (nh, qi-2)
  const int nh = bx / 14, qi = 2 + (bx % 14);
  const int nch = (qi + 2) >> 1;                       // 2..8 chunks
  const int off = (qi * (qi + 2) + (qi & 1)) >> 2;     // sum_{j<qi} (j+2)>>1
  const int n = nh >> 3, head = nh & 7;
  const int slot0 = nh * CHUNKS_PER_NH + off;

  const int tid = threadIdx.x;
  const int r = tid >> 1, half = tid & 1;

  float mstar = -1e30f;
  for (int c = 0; c < nch; ++c) {
    float2 ml = mlbuf[(slot0 + c) * 128 + r];
    mstar = fmaxf(mstar, ml.x);
  }

  float acc[32];
#pragma unroll
  for (int j = 0; j < 32; ++j) acc[j] = 0.f;
  float Lsum = 0.f;

  for (int c = 0; c < nch; ++c) {
    float2 ml = mlbuf[(slot0 + c) * 128 + r];
    if (ml.y > 0.f) {
      float cf = ml.y * __builtin_amdgcn_exp2f(ml.x - mstar);
      Lsum += cf;
      const uint4* p =
          (const uint4*)(partialO + (size_t)(slot0 + c) * 8192 + r * 64 + half * 32);
#pragma unroll
      for (int u = 0; u < 4; ++u) {
        uint4 d = p[u];
        unsigned w[4] = {d.x, d.y, d.z, d.w};
#pragma unroll
        for (int k = 0; k < 4; ++k) {
          acc[u * 8 + 2 * k] += cf * __uint_as_float(w[k] << 16);
          acc[u * 8 + 2 * k + 1] += cf * __uint_as_float(w[k] & 0xffff0000u);
        }
      }
    }
  }

  const float inv = 1.f / Lsum;
  uint4 outw[4];
#pragma unroll
  for (int u = 0; u < 4; ++u) {
    unsigned ww[4];
#pragma unroll
    for (int k = 0; k < 4; ++k) {
      float e0 = acc[u * 8 + 2 * k] * inv;
      float e1 = acc[u * 8 + 2 * k + 1] * inv;
      ww[k] = ((unsigned)f2b(e0)) | (((unsigned)f2b(e1)) << 16);
    }
    outw[u] = make_uint4(ww[0], ww[1], ww[2], ww[3]);
  }
  ushort* gp = attout + (size_t)(n * SQ + qi * 128 + r) * 512 + head * 64 + half * 32;
#pragma unroll
  for (int u = 0; u < 4; ++u) ((uint4*)gp)[u] = outw[u];
}

// ---------------------------------------------------------------------------
extern "C" void kernel_launch(void* const* d_in, const int* in_sizes, int n_in,
                              void* d_out, int out_size, void* d_ws, size_t ws_size,
                              hipStream_t stream) {
  const float* x = (const float*)d_in[0];
  const int* lens = (const int*)d_in[1];
  const float* Wq = (const float*)d_in[2];
  const float* bq = (const float*)d_in[3];
  const float* Wkv = (const float*)d_in[4];
  const float* bkv = (const float*)d_in[5];
  const float* Wo = (const float*)d_in[6];
  const float* bo = (const float*)d_in[7];
  const float* gamma = (const float*)d_in[8];
  const float* beta = (const float*)d_in[9];
  float* out = (float*)d_out;

  size_t off = 0;
  auto alloc = [&](size_t bytes) {
    void* p = (char*)d_ws + off;
    off += (bytes + 255) & ~(size_t)255;
    return p;
  };
  ushort* xn = (ushort*)alloc((size_t)MROWS * 512 * 2);
  ushort* qbuf = (ushort*)alloc((size_t)MROWS * 512 * 2);
  ushort* kvbuf = (ushort*)alloc((size_t)MROWS * 1024 * 2);
  ushort* WT = (ushort*)alloc((size_t)1536 * 512 * 2);  // [Wq^T ; Wkv^T]
  ushort* WoT = (ushort*)alloc((size_t)512 * 512 * 2);
  ushort* partialO = (ushort*)alloc((size_t)NSLOTS * 8192 * 2);  // 37.7 MB
  float2* mlbuf = (float2*)alloc((size_t)NSLOTS * 128 * 8);      // 2.4 MB
  ushort* attout = xn;  // xn dead after the QKV GEMM (stream-ordered)

  transpose_all<<<dim3(1024), 256, 0, stream>>>(Wq, Wkv, Wo, WT, WoT);

  ln_kernel<<<MROWS / 4, 256, 0, stream>>>(x, gamma, beta, xn);

  // Q pre-scaled by 1/sqrt(dq) * log2(e) so attention uses exp2 directly
  qkv_gemm<<<dim3(12, 64), 256, 0, stream>>>(xn, WT, bq, bkv, qbuf, kvbuf,
                                             0.125f * 1.44269504f);

  attn_kernel<<<dim3(NSLOTS), 256, 0, stream>>>(qbuf, kvbuf, lens, partialO,
                                                mlbuf, attout);
  attn_combine<<<dim3(448), 256, 0, stream>>>(partialO, mlbuf, attout);

  o_gemm<<<dim3(4, 64), 256, 0, stream>>>(attout, WoT, bo, x, out);
}

// Round 9
// 114.156 us; speedup vs baseline: 2.3406x; 1.0450x over previous
//
#include <hip/hip_runtime.h>
#include <hip/hip_bf16.h>

typedef __attribute__((ext_vector_type(4))) float f32x4;
typedef __attribute__((ext_vector_type(16))) float f32x16;
typedef __attribute__((ext_vector_type(8))) short short8;

#define D_MODEL 512
#define SQ 2048
#define NH 8
#define NBATCH 4
#define MROWS (NBATCH * SQ)  // 8192

// split-K chunking: per qi (0..15), T=4*qi+4 tiles split into nch=(qi+2)>>1
// balanced chunks (sizes 4..8). Blocks per (n,h) = sum nch = 72.
#define CHUNKS_PER_NH 72
#define NSLOTS (32 * CHUNKS_PER_NH)  // 2304

__device__ __forceinline__ ushort f2b(float x) {
  unsigned int u = __float_as_uint(x);
  return (ushort)((u + 0x7fffu + ((u >> 16) & 1u)) >> 16);
}

__device__ __forceinline__ f32x4 mfma16(short8 a, short8 b, f32x4 c) {
  return __builtin_amdgcn_mfma_f32_16x16x32_bf16(a, b, c, 0, 0, 0);
}
__device__ __forceinline__ f32x16 mfma32(short8 a, short8 b, f32x16 c) {
  return __builtin_amdgcn_mfma_f32_32x32x16_bf16(a, b, c, 0, 0, 0);
}

#define GLOAD_LDS16(g, l)                                                      \
  __builtin_amdgcn_global_load_lds(                                            \
      (const __attribute__((address_space(1))) unsigned int*)(g),              \
      (__attribute__((address_space(3))) unsigned int*)(l), 16, 0, 0)

// ---------------------------------------------------------------------------
// Fused prep: weight transposes (blocks 0..1023) + LayerNorm (1024..3071).
// Transpose map: [0,256) Wq(512x512), [256,768) Wkv(512x1024),
// [768,1024) Wo(512x512) -> bf16 W^T. LN: one wave per row of 512.
// ---------------------------------------------------------------------------
__global__ __launch_bounds__(256) void prep_kernel(
    const float* __restrict__ Wq, const float* __restrict__ Wkv,
    const float* __restrict__ Wo, ushort* __restrict__ WT,
    ushort* __restrict__ WoT, const float* __restrict__ x,
    const float* __restrict__ gamma, const float* __restrict__ beta,
    ushort* __restrict__ xn) {
  if (blockIdx.x < 1024) {
    __shared__ ushort tile[32][33];
    int b = blockIdx.x;
    const float* W;
    ushort* D;
    int N;
    if (b < 256) {
      W = Wq; D = WT; N = 512;
    } else if (b < 768) {
      W = Wkv; D = WT + 512 * 512; N = 1024; b -= 256;
    } else {
      W = Wo; D = WoT; N = 512; b -= 768;
    }
    const int ntx = N >> 5;
    int n0 = (b % ntx) * 32, k0 = (b / ntx) * 32;
    int tx = threadIdx.x & 31, ty = threadIdx.x >> 5;
#pragma unroll
    for (int i = 0; i < 4; ++i) {
      int k = ty + i * 8;
      tile[tx][k] = f2b(W[(size_t)(k0 + k) * N + n0 + tx]);
    }
    __syncthreads();
#pragma unroll
    for (int i = 0; i < 4; ++i) {
      int nn = ty + i * 8;
      D[(size_t)(n0 + nn) * 512 + k0 + tx] = tile[nn][tx];
    }
    return;
  }

  // ---- LayerNorm part ----
  int wid = threadIdx.x >> 6, lane = threadIdx.x & 63;
  int row = (blockIdx.x - 1024) * 4 + wid;
  const float4* xr = (const float4*)(x + (size_t)row * D_MODEL);
  float4 v0 = xr[lane];
  float4 v1 = xr[lane + 64];
  float s = v0.x + v0.y + v0.z + v0.w + v1.x + v1.y + v1.z + v1.w;
  float q = v0.x * v0.x + v0.y * v0.y + v0.z * v0.z + v0.w * v0.w +
            v1.x * v1.x + v1.y * v1.y + v1.z * v1.z + v1.w * v1.w;
#pragma unroll
  for (int m = 1; m < 64; m <<= 1) {
    s += __shfl_xor(s, m, 64);
    q += __shfl_xor(q, m, 64);
  }
  float mu = s * (1.f / 512.f);
  float var = q * (1.f / 512.f) - mu * mu;
  float rs = rsqrtf(var + 1e-5f);
  const float4* g4 = (const float4*)gamma;
  const float4* b4 = (const float4*)beta;
  ushort* out = xn + (size_t)row * D_MODEL;
#pragma unroll
  for (int i = 0; i < 2; ++i) {
    float4 v = i ? v1 : v0;
    float4 gg = g4[lane + i * 64];
    float4 bb = b4[lane + i * 64];
    ushort4 o;
    o.x = f2b((v.x - mu) * rs * gg.x + bb.x);
    o.y = f2b((v.y - mu) * rs * gg.y + bb.y);
    o.z = f2b((v.z - mu) * rs * gg.z + bb.z);
    o.w = f2b((v.w - mu) * rs * gg.w + bb.w);
    *(ushort4*)(out + (lane + i * 64) * 4) = o;
  }
}

// ---------------------------------------------------------------------------
// Fused Q+KV projection GEMM (m97 structure).
// ---------------------------------------------------------------------------
__global__ __launch_bounds__(256) void qkv_gemm(
    const ushort* __restrict__ A, const ushort* __restrict__ BT,
    const float* __restrict__ bq, const float* __restrict__ bkv,
    ushort* __restrict__ qbuf, ushort* __restrict__ kvbuf, float qscale) {
  __shared__ __align__(16) ushort As[128 * 32];
  __shared__ __align__(16) ushort Bs[128 * 32];
  const int tid = threadIdx.x, lane = tid & 63, wid = tid >> 6;
  const int g = lane >> 4, r = lane & 15;
  const int wr = wid >> 1, wc = wid & 1;
  const int bm = blockIdx.y * 128, bn = blockIdx.x * 128;

  f32x4 acc[4][4];
#pragma unroll
  for (int a = 0; a < 4; ++a)
#pragma unroll
    for (int b = 0; b < 4; ++b) acc[a][b] = (f32x4){0.f, 0.f, 0.f, 0.f};

  const int srow = 32 * wid + (lane >> 2);
  const int scol = (lane & 3) * 8;
  const ushort* ga = A + (size_t)(bm + srow) * 512 + scol;
  const ushort* gb = BT + (size_t)(bn + srow) * 512 + scol;
  ushort* la = As + 32 * 32 * wid;
  ushort* lb = Bs + 32 * 32 * wid;

  for (int kb = 0; kb < 512; kb += 32) {
    __syncthreads();
    GLOAD_LDS16(ga + kb, la);
    GLOAD_LDS16(ga + kb + 16 * 512, la + 16 * 32);
    GLOAD_LDS16(gb + kb, lb);
    GLOAD_LDS16(gb + kb + 16 * 512, lb + 16 * 32);
    __syncthreads();
    short8 af[4], bf[4];
#pragma unroll
    for (int i2 = 0; i2 < 4; ++i2) {
      af[i2] = *(const short8*)&As[(wr * 64 + i2 * 16 + r) * 32 + g * 8];
      bf[i2] = *(const short8*)&Bs[(wc * 64 + i2 * 16 + r) * 32 + g * 8];
    }
#pragma unroll
    for (int a = 0; a < 4; ++a)
#pragma unroll
      for (int b = 0; b < 4; ++b) acc[a][b] = mfma16(af[a], bf[b], acc[a][b]);
  }

  const bool isQ = (bn < 512);
  const float* bias = isQ ? bq : bkv;
  ushort* dst = isQ ? qbuf : kvbuf;
  const int cb = isQ ? bn : bn - 512;
  const size_t stride = isQ ? 512 : 1024;
  const float scale = isQ ? qscale : 1.0f;

#pragma unroll
  for (int a = 0; a < 4; ++a) {
#pragma unroll
    for (int reg = 0; reg < 4; ++reg) {
      int row = bm + wr * 64 + a * 16 + g * 4 + reg;
#pragma unroll
      for (int b = 0; b < 4; ++b) {
        int col = cb + wc * 64 + b * 16 + r;
        dst[(size_t)row * stride + col] = f2b((acc[a][b][reg] + bias[col]) * scale);
      }
    }
  }
}

// ---------------------------------------------------------------------------
// Output-projection GEMM (m97 structure), fp32 out with residual.
// ---------------------------------------------------------------------------
__global__ __launch_bounds__(256) void o_gemm(
    const ushort* __restrict__ A, const ushort* __restrict__ BT,
    const float* __restrict__ bias, const float* __restrict__ resid,
    float* __restrict__ outF) {
  __shared__ __align__(16) ushort As[128 * 32];
  __shared__ __align__(16) ushort Bs[128 * 32];
  const int tid = threadIdx.x, lane = tid & 63, wid = tid >> 6;
  const int g = lane >> 4, r = lane & 15;
  const int wr = wid >> 1, wc = wid & 1;
  const int bm = blockIdx.y * 128, bn = blockIdx.x * 128;

  f32x4 acc[4][4];
#pragma unroll
  for (int a = 0; a < 4; ++a)
#pragma unroll
    for (int b = 0; b < 4; ++b) acc[a][b] = (f32x4){0.f, 0.f, 0.f, 0.f};

  const int srow = 32 * wid + (lane >> 2);
  const int scol = (lane & 3) * 8;
  const ushort* ga = A + (size_t)(bm + srow) * 512 + scol;
  const ushort* gb = BT + (size_t)(bn + srow) * 512 + scol;
  ushort* la = As + 32 * 32 * wid;
  ushort* lb = Bs + 32 * 32 * wid;

  for (int kb = 0; kb < 512; kb += 32) {
    __syncthreads();
    GLOAD_LDS16(ga + kb, la);
    GLOAD_LDS16(ga + kb + 16 * 512, la + 16 * 32);
    GLOAD_LDS16(gb + kb, lb);
    GLOAD_LDS16(gb + kb + 16 * 512, lb + 16 * 32);
    __syncthreads();
    short8 af[4], bf[4];
#pragma unroll
    for (int i2 = 0; i2 < 4; ++i2) {
      af[i2] = *(const short8*)&As[(wr * 64 + i2 * 16 + r) * 32 + g * 8];
      bf[i2] = *(const short8*)&Bs[(wc * 64 + i2 * 16 + r) * 32 + g * 8];
    }
#pragma unroll
    for (int a = 0; a < 4; ++a)
#pragma unroll
      for (int b = 0; b < 4; ++b) acc[a][b] = mfma16(af[a], bf[b], acc[a][b]);
  }

#pragma unroll
  for (int a = 0; a < 4; ++a) {
#pragma unroll
    for (int reg = 0; reg < 4; ++reg) {
      int row = bm + wr * 64 + a * 16 + g * 4 + reg;
#pragma unroll
      for (int b = 0; b < 4; ++b) {
        int col = bn + wc * 64 + b * 16 + r;
        outF[(size_t)row * 512 + col] =
            acc[a][b][reg] + bias[col] + resid[(size_t)row * 512 + col];
      }
    }
  }
}

// ---------------------------------------------------------------------------
// Flash attention, split-K (R3 core). Per (n,h): 72 chunk-blocks; 4 waves x
// 32 q-rows; 32-key tiles; depth-2 prefetched reg-staged K/V; XCD-balanced
// swizzle; LPT dispatch order. nch==1 groups (qi 0,1) write attout directly;
// others write partialO + (m,l) for the combine kernel.
// ---------------------------------------------------------------------------
__global__ __launch_bounds__(256) void attn_kernel(
    const ushort* __restrict__ qbuf, const ushort* __restrict__ kvbuf,
    const int* __restrict__ lengths, ushort* __restrict__ partialO,
    float2* __restrict__ mlbuf, ushort* __restrict__ attout) {
  __shared__ __align__(16) ushort smem[9728];
  // Kt buf b: smem + b*2304   ([32][72])
  // Vt buf b: smem + 4608 + b*2560  ([64][40], 16B-unit XOR swizzle)

  const int tid = threadIdx.x, lane = tid & 63, wid = tid >> 6;
  const int l31 = lane & 31, h = lane >> 5;

  const int bid = blockIdx.x;
  const int xcd = bid & 7;
  const int j = bid >> 3;          // 0..287
  const int grp = j / 72;          // batch index
  const int L = 71 - (j - grp * 72);  // chunk within (n,h), reversed (LPT)
  const int nh = (grp << 3) | xcd;
  const int n = nh >> 3, head = nh & 7;
  int qi = 0, c = L;
  while (c >= ((qi + 2) >> 1)) { c -= (qi + 2) >> 1; ++qi; }
  const int T = 4 * qi + 4, nch = (qi + 2) >> 1;
  const int t0 = (c * T) / nch;
  const int t1 = ((c + 1) * T) / nch;
  const int slot = nh * CHUNKS_PER_NH + L;

  const int qb = qi * 128;
  const int len = lengths[n];
  const int q0w = qb + 32 * wid;
  const int q_own = q0w + l31;
  const int nt_w_abs = 4 * qi + wid + 1;  // wave computes tiles t < this
  const int tlen = (len + 31) >> 5;
  int nt = min(t1, tlen) - t0;
  if (nt < 0) nt = 0;

  f32x16 o0, o1;
#pragma unroll
  for (int i = 0; i < 16; ++i) { o0[i] = 0.f; o1[i] = 0.f; }
  float m_ = -1e30f, ls = 0.f;

  const int skey = tid >> 3, sc8 = tid & 7;               // K staging
  const int kp = lane & 15, dvb = wid * 4 + (lane >> 4);  // V staging
  const int mu = (l31 >> 2) & 3;                          // V-unit swizzle key

  int voff[4];
#pragma unroll
  for (int jj = 0; jj < 4; ++jj) {
    int dv = 4 * dvb + jj;
    voff[jj] = dv * 20 + (((kp >> 2) ^ ((dv >> 2) & 3)) << 2) + (kp & 3);
  }

  const ushort* kvbase = kvbuf + (size_t)n * SQ * 1024 + head * 64;
  const ushort* kSrc = kvbase + (size_t)(t0 * 32 + skey) * 1024 + sc8 * 8;
  const ushort* vSrc = kvbase + 512 + (size_t)(t0 * 32 + 2 * kp) * 1024 + dvb * 4;
  const int kLdsOff = skey * 72 + sc8 * 8;

  if (nt > 0) {
    // Q fragments (persistent): B-frag col=q=l31, k = 16kc + 8h + e
    short8 qf[4];
    {
      const ushort* qp = qbuf + (size_t)(n * SQ + q_own) * 512 + head * 64 + 8 * h;
#pragma unroll
      for (int kc = 0; kc < 4; ++kc) qf[kc] = *(const short8*)(qp + 16 * kc);
    }

    // two register staging sets; tile t lives in set (t-t0)&1
    uint4 kA, kB = {};
    uint2 vaA, vbA, vaB = {}, vbB = {};
    kA = *(const uint4*)kSrc;
    vaA = *(const uint2*)vSrc;
    vbA = *(const uint2*)(vSrc + 1024);
    kSrc += 32 * 1024;
    vSrc += 32 * 1024;
    if (nt > 1) {
      kB = *(const uint4*)kSrc;
      vaB = *(const uint2*)vSrc;
      vbB = *(const uint2*)(vSrc + 1024);
      kSrc += 32 * 1024;
      vSrc += 32 * 1024;
    }
    {  // write tile 0 (set A) into buffer 0
      *(uint4*)(smem + kLdsOff) = kA;
      const ushort* a16 = (const ushort*)&vaA;
      const ushort* b16 = (const ushort*)&vbA;
#pragma unroll
      for (int jj = 0; jj < 4; ++jj)
        ((unsigned*)(smem + 4608))[voff[jj]] =
            (unsigned)a16[jj] | ((unsigned)b16[jj] << 16);
    }
    __syncthreads();

    for (int i = 0; i < nt; ++i) {
      const int t = t0 + i;
      const int cur = i & 1;
      if (i + 2 < nt) {  // issue loads 2 tiles ahead into the freed set
        if (cur == 0) {
          kA = *(const uint4*)kSrc;
          vaA = *(const uint2*)vSrc;
          vbA = *(const uint2*)(vSrc + 1024);
        } else {
          kB = *(const uint4*)kSrc;
          vaB = *(const uint2*)vSrc;
          vbB = *(const uint2*)(vSrc + 1024);
        }
        kSrc += 32 * 1024;
        vSrc += 32 * 1024;
      }

      if (t < nt_w_abs) {
        const int kb = t * 32;
        const ushort* KtB = smem + cur * 2304;
        const ushort* VtB = smem + 4608 + cur * 2560;

        // QK^T swapped: S^T[key][q], col=q=l31, key(reg)=(reg&3)+8*(reg>>2)+4h
        f32x16 s;
#pragma unroll
        for (int i2 = 0; i2 < 16; ++i2) s[i2] = 0.f;
        {
          const ushort* kr_ = KtB + l31 * 72 + 8 * h;
          short8 k0 = *(const short8*)(kr_);
          short8 k1 = *(const short8*)(kr_ + 16);
          short8 k2 = *(const short8*)(kr_ + 32);
          short8 k3 = *(const short8*)(kr_ + 48);
          __builtin_amdgcn_s_setprio(1);
          s = mfma32(k0, qf[0], s);
          s = mfma32(k1, qf[1], s);
          s = mfma32(k2, qf[2], s);
          s = mfma32(k3, qf[3], s);
          __builtin_amdgcn_s_setprio(0);
        }

        // boundary tiles only: causal + length mask
        if (kb + 31 > q0w || kb + 31 >= len) {
          int keyb = kb + 4 * h;
#pragma unroll
          for (int reg = 0; reg < 16; ++reg) {
            int key = keyb + (reg & 3) + 8 * (reg >> 2);
            bool ok = (key <= q_own) && (key < len);
            s[reg] = ok ? s[reg] : -1e30f;
          }
        }

        // max-reduce as v_max3-fusable tree
        float a0 = fmaxf(fmaxf(s[0], s[1]), s[2]);
        float a1 = fmaxf(fmaxf(s[3], s[4]), s[5]);
        float a2 = fmaxf(fmaxf(s[6], s[7]), s[8]);
        float a3 = fmaxf(fmaxf(s[9], s[10]), s[11]);
        float a4 = fmaxf(fmaxf(s[12], s[13]), s[14]);
        float mx = fmaxf(fmaxf(fmaxf(a0, a1), s[15]),
                         fmaxf(fmaxf(a2, a3), a4));
        {
          auto rr = __builtin_amdgcn_permlane32_swap(__float_as_uint(mx),
                                                     __float_as_uint(mx), false, false);
          mx = fmaxf(__uint_as_float(((const unsigned*)&rr)[0]),
                     __uint_as_float(((const unsigned*)&rr)[1]));
        }

        if (!__all(mx <= m_ + 8.0f)) {
          float mn = fmaxf(m_, mx);
          float sf = __builtin_amdgcn_exp2f(m_ - mn);
          m_ = mn;
          ls *= sf;
#pragma unroll
          for (int i2 = 0; i2 < 16; ++i2) { o0[i2] *= sf; o1[i2] *= sf; }
        }

        float p[16];
#pragma unroll
        for (int reg = 0; reg < 16; ++reg)
          p[reg] = __builtin_amdgcn_exp2f(s[reg] - m_);

        float rsum = ((p[0] + p[1]) + (p[2] + p[3])) + ((p[4] + p[5]) + (p[6] + p[7])) +
                     ((p[8] + p[9]) + (p[10] + p[11])) +
                     ((p[12] + p[13]) + (p[14] + p[15]));
        {
          auto rr = __builtin_amdgcn_permlane32_swap(__float_as_uint(rsum),
                                                     __float_as_uint(rsum), false, false);
          rsum = __uint_as_float(((const unsigned*)&rr)[0]) +
                 __uint_as_float(((const unsigned*)&rr)[1]);
        }
        ls += rsum;

        unsigned pk[8];
#pragma unroll
        for (int jj = 0; jj < 8; ++jj)
          pk[jj] = __builtin_amdgcn_perm(__float_as_uint(p[2 * jj + 1]),
                                         __float_as_uint(p[2 * jj]), 0x07060302u);

        // PV: B-frag = own pk words (k-slot sigma(h,e)=16kc+4h+(e&3)+8(e>>2))
        __builtin_amdgcn_s_setprio(1);
#pragma unroll
        for (int kc = 0; kc < 2; ++kc) {
          short8 pf;
          ((unsigned*)&pf)[0] = pk[4 * kc + 0];
          ((unsigned*)&pf)[1] = pk[4 * kc + 1];
          ((unsigned*)&pf)[2] = pk[4 * kc + 2];
          ((unsigned*)&pf)[3] = pk[4 * kc + 3];
          const int u0 = ((2 * kc) ^ mu) << 3;
          const ushort* vb0 = VtB + l31 * 40 + 4 * h;
          const ushort* vb1 = VtB + (32 + l31) * 40 + 4 * h;
          short8 vf0, vf1;
          ((uint2*)&vf0)[0] = *(const uint2*)(vb0 + u0);
          ((uint2*)&vf0)[1] = *(const uint2*)(vb0 + (u0 ^ 8));
          ((uint2*)&vf1)[0] = *(const uint2*)(vb1 + u0);
          ((uint2*)&vf1)[1] = *(const uint2*)(vb1 + (u0 ^ 8));
          o0 = mfma32(vf0, pf, o0);
          o1 = mfma32(vf1, pf, o1);
        }
        __builtin_amdgcn_s_setprio(0);
      }

      if (i + 1 < nt) {  // write tile i+1's regs (in flight ~1 iteration)
        ushort* KtN = smem + (cur ^ 1) * 2304;
        unsigned* VtN = (unsigned*)(smem + 4608 + (cur ^ 1) * 2560);
        if (cur == 0) {
          *(uint4*)(KtN + kLdsOff) = kB;
          const ushort* a16 = (const ushort*)&vaB;
          const ushort* b16 = (const ushort*)&vbB;
#pragma unroll
          for (int jj = 0; jj < 4; ++jj)
            VtN[voff[jj]] = (unsigned)a16[jj] | ((unsigned)b16[jj] << 16);
        } else {
          *(uint4*)(KtN + kLdsOff) = kA;
          const ushort* a16 = (const ushort*)&vaA;
          const ushort* b16 = (const ushort*)&vbA;
#pragma unroll
          for (int jj = 0; jj < 4; ++jj)
            VtN[voff[jj]] = (unsigned)a16[jj] | ((unsigned)b16[jj] << 16);
        }
      }
      __syncthreads();
    }
  }

  // epilogue: normalize partial, transpose via LDS, store.
  const unsigned long long alive = __ballot(ls > 0.f);
  {
    float inv = (ls > 0.f) ? 1.f / ls : 0.f;
    ushort* OtW = smem + wid * (32 * 68);
#pragma unroll
    for (int b = 0; b < 2; ++b) {
#pragma unroll
      for (int reg = 0; reg < 16; reg += 2) {
        float e0 = (b ? o1[reg] : o0[reg]) * inv;
        float e1 = (b ? o1[reg + 1] : o0[reg + 1]) * inv;
        unsigned pko = __builtin_amdgcn_perm(__float_as_uint(e1),
                                             __float_as_uint(e0), 0x07060302u);
        int dv = 32 * b + (reg & 3) + 8 * (reg >> 2) + 4 * h;
        *(unsigned*)(OtW + l31 * 68 + dv) = pko;
      }
    }
    if (h == 0 && nch > 1)
      mlbuf[slot * 128 + 32 * wid + l31] = make_float2(m_, ls);
  }
  __syncthreads();

  if (nch == 1) {
    // qi 0/1: single chunk covers keys from 0; all rows live. Direct store.
    int r = lane >> 1, sg = lane & 1;
    const ushort* rp = smem + wid * (32 * 68) + r * 68 + sg * 32;
    uint2 d0 = *(const uint2*)(rp);
    uint2 d1 = *(const uint2*)(rp + 4);
    uint2 d2 = *(const uint2*)(rp + 8);
    uint2 d3 = *(const uint2*)(rp + 12);
    uint2 d4 = *(const uint2*)(rp + 16);
    uint2 d5 = *(const uint2*)(rp + 20);
    uint2 d6 = *(const uint2*)(rp + 24);
    uint2 d7 = *(const uint2*)(rp + 28);
    ushort* gp = attout + (size_t)(n * SQ + qb + 32 * wid + r) * 512 +
                 head * 64 + sg * 32;
    *(uint4*)(gp) = make_uint4(d0.x, d0.y, d1.x, d1.y);
    *(uint4*)(gp + 8) = make_uint4(d2.x, d2.y, d3.x, d3.y);
    *(uint4*)(gp + 16) = make_uint4(d4.x, d4.y, d5.x, d5.y);
    *(uint4*)(gp + 24) = make_uint4(d6.x, d6.y, d7.x, d7.y);
    return;
  }

  if (alive) {
    int r = lane >> 1, sg = lane & 1;
    if ((alive >> r) & 1ULL) {
      const ushort* rp = smem + wid * (32 * 68) + r * 68 + sg * 32;
      uint2 d0 = *(const uint2*)(rp);
      uint2 d1 = *(const uint2*)(rp + 4);
      uint2 d2 = *(const uint2*)(rp + 8);
      uint2 d3 = *(const uint2*)(rp + 12);
      uint2 d4 = *(const uint2*)(rp + 16);
      uint2 d5 = *(const uint2*)(rp + 20);
      uint2 d6 = *(const uint2*)(rp + 24);
      uint2 d7 = *(const uint2*)(rp + 28);
      ushort* gp = partialO + (size_t)slot * 8192 + (32 * wid + r) * 64 + sg * 32;
      *(uint4*)(gp) = make_uint4(d0.x, d0.y, d1.x, d1.y);
      *(uint4*)(gp + 8) = make_uint4(d2.x, d2.y, d3.x, d3.y);
      *(uint4*)(gp + 16) = make_uint4(d4.x, d4.y, d5.x, d5.y);
      *(uint4*)(gp + 24) = make_uint4(d6.x, d6.y, d7.x, d7.y);
    }
  }
}

// ---------------------------------------------------------------------------
// Split-K combine for qi >= 2 (nch 2..8). Finer-grained: one block per
// (nh, qi, 64-row half) -> 896 blocks; each thread merges 16 floats.
// out = sum_c coef_c * Onorm_c / sum_c coef_c,  coef_c = l_c*exp2(m_c - m*).
// ---------------------------------------------------------------------------
__global__ __launch_bounds__(256) void attn_combine(
    const ushort* __restrict__ partialO, const float2* __restrict__ mlbuf,
    ushort* __restrict__ attout) {
  const int bx = blockIdx.x;  // (group, rowhalf)
  const int gidx = bx >> 1, rowhalf = bx & 1;
  const int nh = gidx / 14, qi = 2 + (gidx % 14);
  const int nch = (qi + 2) >> 1;                       // 2..8 chunks
  const int off = (qi * (qi + 2) + (qi & 1)) >> 2;     // sum_{j<qi} (j+2)>>1
  const int n = nh >> 3, head = nh & 7;
  const int slot0 = nh * CHUNKS_PER_NH + off;

  const int tid = threadIdx.x;
  const int r = rowhalf * 64 + (tid >> 2);  // 0..127
  const int quarter = tid & 3;              // 16-col slice

  float mstar = -1e30f;
  for (int c = 0; c < nch; ++c) {
    float2 ml = mlbuf[(slot0 + c) * 128 + r];
    mstar = fmaxf(mstar, ml.x);
  }

  float acc[16];
#pragma unroll
  for (int j = 0; j < 16; ++j) acc[j] = 0.f;
  float Lsum = 0.f;

  for (int c = 0; c < nch; ++c) {
    float2 ml = mlbuf[(slot0 + c) * 128 + r];
    if (ml.y > 0.f) {
      float cf = ml.y * __builtin_amdgcn_exp2f(ml.x - mstar);
      Lsum += cf;
      const uint4* p =
          (const uint4*)(partialO + (size_t)(slot0 + c) * 8192 + r * 64 + quarter * 16);
#pragma unroll
      for (int u = 0; u < 2; ++u) {
        uint4 d = p[u];
        unsigned w[4] = {d.x, d.y, d.z, d.w};
#pragma unroll
        for (int k = 0; k < 4; ++k) {
          acc[u * 8 + 2 * k] += cf * __uint_as_float(w[k] << 16);
          acc[u * 8 + 2 * k + 1] += cf * __uint_as_float(w[k] & 0xffff0000u);
        }
      }
    }
  }

  const float inv = 1.f / Lsum;
  uint4 outw[2];
#pragma unroll
  for (int u = 0; u < 2; ++u) {
    unsigned ww[4];
#pragma unroll
    for (int k = 0; k < 4; ++k) {
      float e0 = acc[u * 8 + 2 * k] * inv;
      float e1 = acc[u * 8 + 2 * k + 1] * inv;
      ww[k] = ((unsigned)f2b(e0)) | (((unsigned)f2b(e1)) << 16);
    }
    outw[u] = make_uint4(ww[0], ww[1], ww[2], ww[3]);
  }
  ushort* gp = attout + (size_t)(n * SQ + qi * 128 + r) * 512 + head * 64 + quarter * 16;
  ((uint4*)gp)[0] = outw[0];
  ((uint4*)gp)[1] = outw[1];
}

// ---------------------------------------------------------------------------
extern "C" void kernel_launch(void* const* d_in, const int* in_sizes, int n_in,
                              void* d_out, int out_size, void* d_ws, size_t ws_size,
                              hipStream_t stream) {
  const float* x = (const float*)d_in[0];
  const int* lens = (const int*)d_in[1];
  const float* Wq = (const float*)d_in[2];
  const float* bq = (const float*)d_in[3];
  const float* Wkv = (const float*)d_in[4];
  const float* bkv = (const float*)d_in[5];
  const float* Wo = (const float*)d_in[6];
  const float* bo = (const float*)d_in[7];
  const float* gamma = (const float*)d_in[8];
  const float* beta = (const float*)d_in[9];
  float* out = (float*)d_out;

  size_t off = 0;
  auto alloc = [&](size_t bytes) {
    void* p = (char*)d_ws + off;
    off += (bytes + 255) & ~(size_t)255;
    return p;
  };
  ushort* xn = (ushort*)alloc((size_t)MROWS * 512 * 2);
  ushort* qbuf = (ushort*)alloc((size_t)MROWS * 512 * 2);
  ushort* kvbuf = (ushort*)alloc((size_t)MROWS * 1024 * 2);
  ushort* WT = (ushort*)alloc((size_t)1536 * 512 * 2);  // [Wq^T ; Wkv^T]
  ushort* WoT = (ushort*)alloc((size_t)512 * 512 * 2);
  ushort* partialO = (ushort*)alloc((size_t)NSLOTS * 8192 * 2);  // 37.7 MB
  float2* mlbuf = (float2*)alloc((size_t)NSLOTS * 128 * 8);      // 2.4 MB
  ushort* attout = xn;  // xn dead after the QKV GEMM (stream-ordered)

  prep_kernel<<<dim3(1024 + MROWS / 4), 256, 0, stream>>>(
      Wq, Wkv, Wo, WT, WoT, x, gamma, beta, xn);

  // Q pre-scaled by 1/sqrt(dq) * log2(e) so attention uses exp2 directly
  qkv_gemm<<<dim3(12, 64), 256, 0, stream>>>(xn, WT, bq, bkv, qbuf, kvbuf,
                                             0.125f * 1.44269504f);

  attn_kernel<<<dim3(NSLOTS), 256, 0, stream>>>(qbuf, kvbuf, lens, partialO,
                                                mlbuf, attout);
  attn_combine<<<dim3(896), 256, 0, stream>>>(partialO, mlbuf, attout);

  o_gemm<<<dim3(4, 64), 256, 0, stream>>>(attout, WoT, bo, x, out);
}

// Round 10
// 108.237 us; speedup vs baseline: 2.4686x; 1.0547x over previous
//
#include <hip/hip_runtime.h>
#include <hip/hip_bf16.h>

typedef __attribute__((ext_vector_type(4))) float f32x4;
typedef __attribute__((ext_vector_type(16))) float f32x16;
typedef __attribute__((ext_vector_type(8))) short short8;

#define D_MODEL 512
#define SQ 2048
#define NH 8
#define NBATCH 4
#define MROWS (NBATCH * SQ)  // 8192

// split-K chunking: per qi (0..15), T=4*qi+4 tiles split into nch=(qi+2)>>1
// balanced chunks (sizes 4..8). Blocks per (n,h) = sum nch = 72.
#define CHUNKS_PER_NH 72
#define NSLOTS (32 * CHUNKS_PER_NH)  // 2304

__device__ __forceinline__ ushort f2b(float x) {
  unsigned int u = __float_as_uint(x);
  return (ushort)((u + 0x7fffu + ((u >> 16) & 1u)) >> 16);
}

__device__ __forceinline__ f32x4 mfma16(short8 a, short8 b, f32x4 c) {
  return __builtin_amdgcn_mfma_f32_16x16x32_bf16(a, b, c, 0, 0, 0);
}
__device__ __forceinline__ f32x16 mfma32(short8 a, short8 b, f32x16 c) {
  return __builtin_amdgcn_mfma_f32_32x32x16_bf16(a, b, c, 0, 0, 0);
}

#define GLOAD_LDS16(g, l)                                                      \
  __builtin_amdgcn_global_load_lds(                                            \
      (const __attribute__((address_space(1))) unsigned int*)(g),              \
      (__attribute__((address_space(3))) unsigned int*)(l), 16, 0, 0)

// ---------------------------------------------------------------------------
// Fused prep: weight transposes (blocks 0..1023) + LayerNorm (1024..3071).
// ---------------------------------------------------------------------------
__global__ __launch_bounds__(256) void prep_kernel(
    const float* __restrict__ Wq, const float* __restrict__ Wkv,
    const float* __restrict__ Wo, ushort* __restrict__ WT,
    ushort* __restrict__ WoT, const float* __restrict__ x,
    const float* __restrict__ gamma, const float* __restrict__ beta,
    ushort* __restrict__ xn) {
  if (blockIdx.x < 1024) {
    __shared__ ushort tile[32][33];
    int b = blockIdx.x;
    const float* W;
    ushort* D;
    int N;
    if (b < 256) {
      W = Wq; D = WT; N = 512;
    } else if (b < 768) {
      W = Wkv; D = WT + 512 * 512; N = 1024; b -= 256;
    } else {
      W = Wo; D = WoT; N = 512; b -= 768;
    }
    const int ntx = N >> 5;
    int n0 = (b % ntx) * 32, k0 = (b / ntx) * 32;
    int tx = threadIdx.x & 31, ty = threadIdx.x >> 5;
#pragma unroll
    for (int i = 0; i < 4; ++i) {
      int k = ty + i * 8;
      tile[tx][k] = f2b(W[(size_t)(k0 + k) * N + n0 + tx]);
    }
    __syncthreads();
#pragma unroll
    for (int i = 0; i < 4; ++i) {
      int nn = ty + i * 8;
      D[(size_t)(n0 + nn) * 512 + k0 + tx] = tile[nn][tx];
    }
    return;
  }

  // ---- LayerNorm part ----
  int wid = threadIdx.x >> 6, lane = threadIdx.x & 63;
  int row = (blockIdx.x - 1024) * 4 + wid;
  const float4* xr = (const float4*)(x + (size_t)row * D_MODEL);
  float4 v0 = xr[lane];
  float4 v1 = xr[lane + 64];
  float s = v0.x + v0.y + v0.z + v0.w + v1.x + v1.y + v1.z + v1.w;
  float q = v0.x * v0.x + v0.y * v0.y + v0.z * v0.z + v0.w * v0.w +
            v1.x * v1.x + v1.y * v1.y + v1.z * v1.z + v1.w * v1.w;
#pragma unroll
  for (int m = 1; m < 64; m <<= 1) {
    s += __shfl_xor(s, m, 64);
    q += __shfl_xor(q, m, 64);
  }
  float mu = s * (1.f / 512.f);
  float var = q * (1.f / 512.f) - mu * mu;
  float rs = rsqrtf(var + 1e-5f);
  const float4* g4 = (const float4*)gamma;
  const float4* b4 = (const float4*)beta;
  ushort* out = xn + (size_t)row * D_MODEL;
#pragma unroll
  for (int i = 0; i < 2; ++i) {
    float4 v = i ? v1 : v0;
    float4 gg = g4[lane + i * 64];
    float4 bb = b4[lane + i * 64];
    ushort4 o;
    o.x = f2b((v.x - mu) * rs * gg.x + bb.x);
    o.y = f2b((v.y - mu) * rs * gg.y + bb.y);
    o.z = f2b((v.z - mu) * rs * gg.z + bb.z);
    o.w = f2b((v.w - mu) * rs * gg.w + bb.w);
    *(ushort4*)(out + (lane + i * 64) * 4) = o;
  }
}

// ---------------------------------------------------------------------------
// Fused Q+KV projection GEMM (m97 structure) with dead-KV-tile skip:
// KV blocks (bn>=512) whose 128 rows are all >= len[batch] are never read
// by attention (keys masked at key<len; last read key tile always starts
// below len), so they exit immediately.
// ---------------------------------------------------------------------------
__global__ __launch_bounds__(256) void qkv_gemm(
    const ushort* __restrict__ A, const ushort* __restrict__ BT,
    const float* __restrict__ bq, const float* __restrict__ bkv,
    ushort* __restrict__ qbuf, ushort* __restrict__ kvbuf, float qscale,
    const int* __restrict__ lens) {
  __shared__ __align__(16) ushort As[128 * 32];
  __shared__ __align__(16) ushort Bs[128 * 32];
  const int tid = threadIdx.x, lane = tid & 63, wid = tid >> 6;
  const int g = lane >> 4, r = lane & 15;
  const int wr = wid >> 1, wc = wid & 1;
  const int bm = blockIdx.y * 128, bn = blockIdx.x * 128;

  const bool isQ = (bn < 512);
  if (!isQ) {
    // dead KV tile skip: all rows of this tile >= len of its batch
    if ((bm & 2047) >= lens[bm >> 11]) return;
  }

  f32x4 acc[4][4];
#pragma unroll
  for (int a = 0; a < 4; ++a)
#pragma unroll
    for (int b = 0; b < 4; ++b) acc[a][b] = (f32x4){0.f, 0.f, 0.f, 0.f};

  const int srow = 32 * wid + (lane >> 2);
  const int scol = (lane & 3) * 8;
  const ushort* ga = A + (size_t)(bm + srow) * 512 + scol;
  const ushort* gb = BT + (size_t)(bn + srow) * 512 + scol;
  ushort* la = As + 32 * 32 * wid;
  ushort* lb = Bs + 32 * 32 * wid;

  for (int kb = 0; kb < 512; kb += 32) {
    __syncthreads();
    GLOAD_LDS16(ga + kb, la);
    GLOAD_LDS16(ga + kb + 16 * 512, la + 16 * 32);
    GLOAD_LDS16(gb + kb, lb);
    GLOAD_LDS16(gb + kb + 16 * 512, lb + 16 * 32);
    __syncthreads();
    short8 af[4], bf[4];
#pragma unroll
    for (int i2 = 0; i2 < 4; ++i2) {
      af[i2] = *(const short8*)&As[(wr * 64 + i2 * 16 + r) * 32 + g * 8];
      bf[i2] = *(const short8*)&Bs[(wc * 64 + i2 * 16 + r) * 32 + g * 8];
    }
#pragma unroll
    for (int a = 0; a < 4; ++a)
#pragma unroll
      for (int b = 0; b < 4; ++b) acc[a][b] = mfma16(af[a], bf[b], acc[a][b]);
  }

  const float* bias = isQ ? bq : bkv;
  ushort* dst = isQ ? qbuf : kvbuf;
  const int cb = isQ ? bn : bn - 512;
  const size_t stride = isQ ? 512 : 1024;
  const float scale = isQ ? qscale : 1.0f;

#pragma unroll
  for (int a = 0; a < 4; ++a) {
#pragma unroll
    for (int reg = 0; reg < 4; ++reg) {
      int row = bm + wr * 64 + a * 16 + g * 4 + reg;
#pragma unroll
      for (int b = 0; b < 4; ++b) {
        int col = cb + wc * 64 + b * 16 + r;
        dst[(size_t)row * stride + col] = f2b((acc[a][b][reg] + bias[col]) * scale);
      }
    }
  }
}

// ---------------------------------------------------------------------------
// Output-projection GEMM, fp32 out with residual. Re-tiled for TLP:
// 128x64 tiles (grid 8x64 = 512 blocks = 2/CU, 8 waves/CU vs previous 4),
// 4 waves as 2x2 of 64x32-output each (acc[4][2]).
// ---------------------------------------------------------------------------
__global__ __launch_bounds__(256) void o_gemm(
    const ushort* __restrict__ A, const ushort* __restrict__ BT,
    const float* __restrict__ bias, const float* __restrict__ resid,
    float* __restrict__ outF) {
  __shared__ __align__(16) ushort As[128 * 32];
  __shared__ __align__(16) ushort Bs[64 * 32];
  const int tid = threadIdx.x, lane = tid & 63, wid = tid >> 6;
  const int g = lane >> 4, r = lane & 15;
  const int wr = wid >> 1, wc = wid & 1;
  const int bm = blockIdx.y * 128, bn = blockIdx.x * 64;

  f32x4 acc[4][2];
#pragma unroll
  for (int a = 0; a < 4; ++a)
#pragma unroll
    for (int b = 0; b < 2; ++b) acc[a][b] = (f32x4){0.f, 0.f, 0.f, 0.f};

  const int scol = (lane & 3) * 8;
  const int srowA = 32 * wid + (lane >> 2);
  const int srowB = 16 * wid + (lane >> 2);
  const ushort* ga = A + (size_t)(bm + srowA) * 512 + scol;
  const ushort* gb = BT + (size_t)(bn + srowB) * 512 + scol;
  ushort* la = As + 32 * 32 * wid;
  ushort* lb = Bs + 16 * 32 * wid;

  for (int kb = 0; kb < 512; kb += 32) {
    __syncthreads();
    GLOAD_LDS16(ga + kb, la);
    GLOAD_LDS16(ga + kb + 16 * 512, la + 16 * 32);
    GLOAD_LDS16(gb + kb, lb);
    __syncthreads();
    short8 af[4], bf[2];
#pragma unroll
    for (int i2 = 0; i2 < 4; ++i2)
      af[i2] = *(const short8*)&As[(wr * 64 + i2 * 16 + r) * 32 + g * 8];
#pragma unroll
    for (int i2 = 0; i2 < 2; ++i2)
      bf[i2] = *(const short8*)&Bs[(wc * 32 + i2 * 16 + r) * 32 + g * 8];
#pragma unroll
    for (int a = 0; a < 4; ++a)
#pragma unroll
      for (int b = 0; b < 2; ++b) acc[a][b] = mfma16(af[a], bf[b], acc[a][b]);
  }

#pragma unroll
  for (int a = 0; a < 4; ++a) {
#pragma unroll
    for (int reg = 0; reg < 4; ++reg) {
      int row = bm + wr * 64 + a * 16 + g * 4 + reg;
#pragma unroll
      for (int b = 0; b < 2; ++b) {
        int col = bn + wc * 32 + b * 16 + r;
        outF[(size_t)row * 512 + col] =
            acc[a][b][reg] + bias[col] + resid[(size_t)row * 512 + col];
      }
    }
  }
}

// ---------------------------------------------------------------------------
// Flash attention, split-K (R3 core). Per (n,h): 72 chunk-blocks; 4 waves x
// 32 q-rows; 32-key tiles; depth-2 prefetched reg-staged K/V; XCD-balanced
// swizzle; LPT dispatch order. nch==1 groups (qi 0,1) write attout directly;
// others write partialO + (m,l) for the combine kernel.
// ---------------------------------------------------------------------------
__global__ __launch_bounds__(256) void attn_kernel(
    const ushort* __restrict__ qbuf, const ushort* __restrict__ kvbuf,
    const int* __restrict__ lengths, ushort* __restrict__ partialO,
    float2* __restrict__ mlbuf, ushort* __restrict__ attout) {
  __shared__ __align__(16) ushort smem[9728];
  // Kt buf b: smem + b*2304   ([32][72])
  // Vt buf b: smem + 4608 + b*2560  ([64][40], 16B-unit XOR swizzle)

  const int tid = threadIdx.x, lane = tid & 63, wid = tid >> 6;
  const int l31 = lane & 31, h = lane >> 5;

  const int bid = blockIdx.x;
  const int xcd = bid & 7;
  const int j = bid >> 3;          // 0..287
  const int grp = j / 72;          // batch index
  const int L = 71 - (j - grp * 72);  // chunk within (n,h), reversed (LPT)
  const int nh = (grp << 3) | xcd;
  const int n = nh >> 3, head = nh & 7;
  int qi = 0, c = L;
  while (c >= ((qi + 2) >> 1)) { c -= (qi + 2) >> 1; ++qi; }
  const int T = 4 * qi + 4, nch = (qi + 2) >> 1;
  const int t0 = (c * T) / nch;
  const int t1 = ((c + 1) * T) / nch;
  const int slot = nh * CHUNKS_PER_NH + L;

  const int qb = qi * 128;
  const int len = lengths[n];
  const int q0w = qb + 32 * wid;
  const int q_own = q0w + l31;
  const int nt_w_abs = 4 * qi + wid + 1;  // wave computes tiles t < this
  const int tlen = (len + 31) >> 5;
  int nt = min(t1, tlen) - t0;
  if (nt < 0) nt = 0;

  f32x16 o0, o1;
#pragma unroll
  for (int i = 0; i < 16; ++i) { o0[i] = 0.f; o1[i] = 0.f; }
  float m_ = -1e30f, ls = 0.f;

  const int skey = tid >> 3, sc8 = tid & 7;               // K staging
  const int kp = lane & 15, dvb = wid * 4 + (lane >> 4);  // V staging
  const int mu = (l31 >> 2) & 3;                          // V-unit swizzle key

  int voff[4];
#pragma unroll
  for (int jj = 0; jj < 4; ++jj) {
    int dv = 4 * dvb + jj;
    voff[jj] = dv * 20 + (((kp >> 2) ^ ((dv >> 2) & 3)) << 2) + (kp & 3);
  }

  const ushort* kvbase = kvbuf + (size_t)n * SQ * 1024 + head * 64;
  const ushort* kSrc = kvbase + (size_t)(t0 * 32 + skey) * 1024 + sc8 * 8;
  const ushort* vSrc = kvbase + 512 + (size_t)(t0 * 32 + 2 * kp) * 1024 + dvb * 4;
  const int kLdsOff = skey * 72 + sc8 * 8;

  if (nt > 0) {
    // Q fragments (persistent): B-frag col=q=l31, k = 16kc + 8h + e
    short8 qf[4];
    {
      const ushort* qp = qbuf + (size_t)(n * SQ + q_own) * 512 + head * 64 + 8 * h;
#pragma unroll
      for (int kc = 0; kc < 4; ++kc) qf[kc] = *(const short8*)(qp + 16 * kc);
    }

    // two register staging sets; tile t lives in set (t-t0)&1
    uint4 kA, kB = {};
    uint2 vaA, vbA, vaB = {}, vbB = {};
    kA = *(const uint4*)kSrc;
    vaA = *(const uint2*)vSrc;
    vbA = *(const uint2*)(vSrc + 1024);
    kSrc += 32 * 1024;
    vSrc += 32 * 1024;
    if (nt > 1) {
      kB = *(const uint4*)kSrc;
      vaB = *(const uint2*)vSrc;
      vbB = *(const uint2*)(vSrc + 1024);
      kSrc += 32 * 1024;
      vSrc += 32 * 1024;
    }
    {  // write tile 0 (set A) into buffer 0
      *(uint4*)(smem + kLdsOff) = kA;
      const ushort* a16 = (const ushort*)&vaA;
      const ushort* b16 = (const ushort*)&vbA;
#pragma unroll
      for (int jj = 0; jj < 4; ++jj)
        ((unsigned*)(smem + 4608))[voff[jj]] =
            (unsigned)a16[jj] | ((unsigned)b16[jj] << 16);
    }
    __syncthreads();

    for (int i = 0; i < nt; ++i) {
      const int t = t0 + i;
      const int cur = i & 1;
      if (i + 2 < nt) {  // issue loads 2 tiles ahead into the freed set
        if (cur == 0) {
          kA = *(const uint4*)kSrc;
          vaA = *(const uint2*)vSrc;
          vbA = *(const uint2*)(vSrc + 1024);
        } else {
          kB = *(const uint4*)kSrc;
          vaB = *(const uint2*)vSrc;
          vbB = *(const uint2*)(vSrc + 1024);
        }
        kSrc += 32 * 1024;
        vSrc += 32 * 1024;
      }

      if (t < nt_w_abs) {
        const int kb = t * 32;
        const ushort* KtB = smem + cur * 2304;
        const ushort* VtB = smem + 4608 + cur * 2560;

        // QK^T swapped: S^T[key][q], col=q=l31, key(reg)=(reg&3)+8*(reg>>2)+4h
        f32x16 s;
#pragma unroll
        for (int i2 = 0; i2 < 16; ++i2) s[i2] = 0.f;
        {
          const ushort* kr_ = KtB + l31 * 72 + 8 * h;
          short8 k0 = *(const short8*)(kr_);
          short8 k1 = *(const short8*)(kr_ + 16);
          short8 k2 = *(const short8*)(kr_ + 32);
          short8 k3 = *(const short8*)(kr_ + 48);
          __builtin_amdgcn_s_setprio(1);
          s = mfma32(k0, qf[0], s);
          s = mfma32(k1, qf[1], s);
          s = mfma32(k2, qf[2], s);
          s = mfma32(k3, qf[3], s);
          __builtin_amdgcn_s_setprio(0);
        }

        // boundary tiles only: causal + length mask
        if (kb + 31 > q0w || kb + 31 >= len) {
          int keyb = kb + 4 * h;
#pragma unroll
          for (int reg = 0; reg < 16; ++reg) {
            int key = keyb + (reg & 3) + 8 * (reg >> 2);
            bool ok = (key <= q_own) && (key < len);
            s[reg] = ok ? s[reg] : -1e30f;
          }
        }

        // max-reduce as v_max3-fusable tree
        float a0 = fmaxf(fmaxf(s[0], s[1]), s[2]);
        float a1 = fmaxf(fmaxf(s[3], s[4]), s[5]);
        float a2 = fmaxf(fmaxf(s[6], s[7]), s[8]);
        float a3 = fmaxf(fmaxf(s[9], s[10]), s[11]);
        float a4 = fmaxf(fmaxf(s[12], s[13]), s[14]);
        float mx = fmaxf(fmaxf(fmaxf(a0, a1), s[15]),
                         fmaxf(fmaxf(a2, a3), a4));
        {
          auto rr = __builtin_amdgcn_permlane32_swap(__float_as_uint(mx),
                                                     __float_as_uint(mx), false, false);
          mx = fmaxf(__uint_as_float(((const unsigned*)&rr)[0]),
                     __uint_as_float(((const unsigned*)&rr)[1]));
        }

        if (!__all(mx <= m_ + 8.0f)) {
          float mn = fmaxf(m_, mx);
          float sf = __builtin_amdgcn_exp2f(m_ - mn);
          m_ = mn;
          ls *= sf;
#pragma unroll
          for (int i2 = 0; i2 < 16; ++i2) { o0[i2] *= sf; o1[i2] *= sf; }
        }

        float p[16];
#pragma unroll
        for (int reg = 0; reg < 16; ++reg)
          p[reg] = __builtin_amdgcn_exp2f(s[reg] - m_);

        float rsum = ((p[0] + p[1]) + (p[2] + p[3])) + ((p[4] + p[5]) + (p[6] + p[7])) +
                     ((p[8] + p[9]) + (p[10] + p[11])) +
                     ((p[12] + p[13]) + (p[14] + p[15]));
        {
          auto rr = __builtin_amdgcn_permlane32_swap(__float_as_uint(rsum),
                                                     __float_as_uint(rsum), false, false);
          rsum = __uint_as_float(((const unsigned*)&rr)[0]) +
                 __uint_as_float(((const unsigned*)&rr)[1]);
        }
        ls += rsum;

        unsigned pk[8];
#pragma unroll
        for (int jj = 0; jj < 8; ++jj)
          pk[jj] = __builtin_amdgcn_perm(__float_as_uint(p[2 * jj + 1]),
                                         __float_as_uint(p[2 * jj]), 0x07060302u);

        // PV: B-frag = own pk words (k-slot sigma(h,e)=16kc+4h+(e&3)+8(e>>2))
        __builtin_amdgcn_s_setprio(1);
#pragma unroll
        for (int kc = 0; kc < 2; ++kc) {
          short8 pf;
          ((unsigned*)&pf)[0] = pk[4 * kc + 0];
          ((unsigned*)&pf)[1] = pk[4 * kc + 1];
          ((unsigned*)&pf)[2] = pk[4 * kc + 2];
          ((unsigned*)&pf)[3] = pk[4 * kc + 3];
          const int u0 = ((2 * kc) ^ mu) << 3;
          const ushort* vb0 = VtB + l31 * 40 + 4 * h;
          const ushort* vb1 = VtB + (32 + l31) * 40 + 4 * h;
          short8 vf0, vf1;
          ((uint2*)&vf0)[0] = *(const uint2*)(vb0 + u0);
          ((uint2*)&vf0)[1] = *(const uint2*)(vb0 + (u0 ^ 8));
          ((uint2*)&vf1)[0] = *(const uint2*)(vb1 + u0);
          ((uint2*)&vf1)[1] = *(const uint2*)(vb1 + (u0 ^ 8));
          o0 = mfma32(vf0, pf, o0);
          o1 = mfma32(vf1, pf, o1);
        }
        __builtin_amdgcn_s_setprio(0);
      }

      if (i + 1 < nt) {  // write tile i+1's regs (in flight ~1 iteration)
        ushort* KtN = smem + (cur ^ 1) * 2304;
        unsigned* VtN = (unsigned*)(smem + 4608 + (cur ^ 1) * 2560);
        if (cur == 0) {
          *(uint4*)(KtN + kLdsOff) = kB;
          const ushort* a16 = (const ushort*)&vaB;
          const ushort* b16 = (const ushort*)&vbB;
#pragma unroll
          for (int jj = 0; jj < 4; ++jj)
            VtN[voff[jj]] = (unsigned)a16[jj] | ((unsigned)b16[jj] << 16);
        } else {
          *(uint4*)(KtN + kLdsOff) = kA;
          const ushort* a16 = (const ushort*)&vaA;
          const ushort* b16 = (const ushort*)&vbA;
#pragma unroll
          for (int jj = 0; jj < 4; ++jj)
            VtN[voff[jj]] = (unsigned)a16[jj] | ((unsigned)b16[jj] << 16);
        }
      }
      __syncthreads();
    }
  }

  // epilogue: normalize partial, transpose via LDS, store.
  const unsigned long long alive = __ballot(ls > 0.f);
  {
    float inv = (ls > 0.f) ? 1.f / ls : 0.f;
    ushort* OtW = smem + wid * (32 * 68);
#pragma unroll
    for (int b = 0; b < 2; ++b) {
#pragma unroll
      for (int reg = 0; reg < 16; reg += 2) {
        float e0 = (b ? o1[reg] : o0[reg]) * inv;
        float e1 = (b ? o1[reg + 1] : o0[reg + 1]) * inv;
        unsigned pko = __builtin_amdgcn_perm(__float_as_uint(e1),
                                             __float_as_uint(e0), 0x07060302u);
        int dv = 32 * b + (reg & 3) + 8 * (reg >> 2) + 4 * h;
        *(unsigned*)(OtW + l31 * 68 + dv) = pko;
      }
    }
    if (h == 0 && nch > 1)
      mlbuf[slot * 128 + 32 * wid + l31] = make_float2(m_, ls);
  }
  __syncthreads();

  if (nch == 1) {
    // qi 0/1: single chunk covers keys from 0; all rows live. Direct store.
    int r = lane >> 1, sg = lane & 1;
    const ushort* rp = smem + wid * (32 * 68) + r * 68 + sg * 32;
    uint2 d0 = *(const uint2*)(rp);
    uint2 d1 = *(const uint2*)(rp + 4);
    uint2 d2 = *(const uint2*)(rp + 8);
    uint2 d3 = *(const uint2*)(rp + 12);
    uint2 d4 = *(const uint2*)(rp + 16);
    uint2 d5 = *(const uint2*)(rp + 20);
    uint2 d6 = *(const uint2*)(rp + 24);
    uint2 d7 = *(const uint2*)(rp + 28);
    ushort* gp = attout + (size_t)(n * SQ + qb + 32 * wid + r) * 512 +
                 head * 64 + sg * 32;
    *(uint4*)(gp) = make_uint4(d0.x, d0.y, d1.x, d1.y);
    *(uint4*)(gp + 8) = make_uint4(d2.x, d2.y, d3.x, d3.y);
    *(uint4*)(gp + 16) = make_uint4(d4.x, d4.y, d5.x, d5.y);
    *(uint4*)(gp + 24) = make_uint4(d6.x, d6.y, d7.x, d7.y);
    return;
  }

  if (alive) {
    int r = lane >> 1, sg = lane & 1;
    if ((alive >> r) & 1ULL) {
      const ushort* rp = smem + wid * (32 * 68) + r * 68 + sg * 32;
      uint2 d0 = *(const uint2*)(rp);
      uint2 d1 = *(const uint2*)(rp + 4);
      uint2 d2 = *(const uint2*)(rp + 8);
      uint2 d3 = *(const uint2*)(rp + 12);
      uint2 d4 = *(const uint2*)(rp + 16);
      uint2 d5 = *(const uint2*)(rp + 20);
      uint2 d6 = *(const uint2*)(rp + 24);
      uint2 d7 = *(const uint2*)(rp + 28);
      ushort* gp = partialO + (size_t)slot * 8192 + (32 * wid + r) * 64 + sg * 32;
      *(uint4*)(gp) = make_uint4(d0.x, d0.y, d1.x, d1.y);
      *(uint4*)(gp + 8) = make_uint4(d2.x, d2.y, d3.x, d3.y);
      *(uint4*)(gp + 16) = make_uint4(d4.x, d4.y, d5.x, d5.y);
      *(uint4*)(gp + 24) = make_uint4(d6.x, d6.y, d7.x, d7.y);
    }
  }
}

// ---------------------------------------------------------------------------
// Split-K combine for qi >= 2 (nch 2..8). One block per (nh, qi, rowhalf);
// each thread merges 16 floats.
// ---------------------------------------------------------------------------
__global__ __launch_bounds__(256) void attn_combine(
    const ushort* __restrict__ partialO, const float2* __restrict__ mlbuf,
    ushort* __restrict__ attout) {
  const int bx = blockIdx.x;  // (group, rowhalf)
  const int gidx = bx >> 1, rowhalf = bx & 1;
  const int nh = gidx / 14, qi = 2 + (gidx % 14);
  const int nch = (qi + 2) >> 1;                       // 2..8 chunks
  const int off = (qi * (qi + 2) + (qi & 1)) >> 2;     // sum_{j<qi} (j+2)>>1
  const int n = nh >> 3, head = nh & 7;
  const int slot0 = nh * CHUNKS_PER_NH + off;

  const int tid = threadIdx.x;
  const int r = rowhalf * 64 + (tid >> 2);  // 0..127
  const int quarter = tid & 3;              // 16-col slice

  float mstar = -1e30f;
  for (int c = 0; c < nch; ++c) {
    float2 ml = mlbuf[(slot0 + c) * 128 + r];
    mstar = fmaxf(mstar, ml.x);
  }

  float acc[16];
#pragma unroll
  for (int j = 0; j < 16; ++j) acc[j] = 0.f;
  float Lsum = 0.f;

  for (int c = 0; c < nch; ++c) {
    float2 ml = mlbuf[(slot0 + c) * 128 + r];
    if (ml.y > 0.f) {
      float cf = ml.y * __builtin_amdgcn_exp2f(ml.x - mstar);
      Lsum += cf;
      const uint4* p =
          (const uint4*)(partialO + (size_t)(slot0 + c) * 8192 + r * 64 + quarter * 16);
#pragma unroll
      for (int u = 0; u < 2; ++u) {
        uint4 d = p[u];
        unsigned w[4] = {d.x, d.y, d.z, d.w};
#pragma unroll
        for (int k = 0; k < 4; ++k) {
          acc[u * 8 + 2 * k] += cf * __uint_as_float(w[k] << 16);
          acc[u * 8 + 2 * k + 1] += cf * __uint_as_float(w[k] & 0xffff0000u);
        }
      }
    }
  }

  const float inv = 1.f / Lsum;
  uint4 outw[2];
#pragma unroll
  for (int u = 0; u < 2; ++u) {
    unsigned ww[4];
#pragma unroll
    for (int k = 0; k < 4; ++k) {
      float e0 = acc[u * 8 + 2 * k] * inv;
      float e1 = acc[u * 8 + 2 * k + 1] * inv;
      ww[k] = ((unsigned)f2b(e0)) | (((unsigned)f2b(e1)) << 16);
    }
    outw[u] = make_uint4(ww[0], ww[1], ww[2], ww[3]);
  }
  ushort* gp = attout + (size_t)(n * SQ + qi * 128 + r) * 512 + head * 64 + quarter * 16;
  ((uint4*)gp)[0] = outw[0];
  ((uint4*)gp)[1] = outw[1];
}

// ---------------------------------------------------------------------------
extern "C" void kernel_launch(void* const* d_in, const int* in_sizes, int n_in,
                              void* d_out, int out_size, void* d_ws, size_t ws_size,
                              hipStream_t stream) {
  const float* x = (const float*)d_in[0];
  const int* lens = (const int*)d_in[1];
  const float* Wq = (const float*)d_in[2];
  const float* bq = (const float*)d_in[3];
  const float* Wkv = (const float*)d_in[4];
  const float* bkv = (const float*)d_in[5];
  const float* Wo = (const float*)d_in[6];
  const float* bo = (const float*)d_in[7];
  const float* gamma = (const float*)d_in[8];
  const float* beta = (const float*)d_in[9];
  float* out = (float*)d_out;

  size_t off = 0;
  auto alloc = [&](size_t bytes) {
    void* p = (char*)d_ws + off;
    off += (bytes + 255) & ~(size_t)255;
    return p;
  };
  ushort* xn = (ushort*)alloc((size_t)MROWS * 512 * 2);
  ushort* qbuf = (ushort*)alloc((size_t)MROWS * 512 * 2);
  ushort* kvbuf = (ushort*)alloc((size_t)MROWS * 1024 * 2);
  ushort* WT = (ushort*)alloc((size_t)1536 * 512 * 2);  // [Wq^T ; Wkv^T]
  ushort* WoT = (ushort*)alloc((size_t)512 * 512 * 2);
  ushort* partialO = (ushort*)alloc((size_t)NSLOTS * 8192 * 2);  // 37.7 MB
  float2* mlbuf = (float2*)alloc((size_t)NSLOTS * 128 * 8);      // 2.4 MB
  ushort* attout = xn;  // xn dead after the QKV GEMM (stream-ordered)

  prep_kernel<<<dim3(1024 + MROWS / 4), 256, 0, stream>>>(
      Wq, Wkv, Wo, WT, WoT, x, gamma, beta, xn);

  // Q pre-scaled by 1/sqrt(dq) * log2(e) so attention uses exp2 directly
  qkv_gemm<<<dim3(12, 64), 256, 0, stream>>>(xn, WT, bq, bkv, qbuf, kvbuf,
                                             0.125f * 1.44269504f, lens);

  attn_kernel<<<dim3(NSLOTS), 256, 0, stream>>>(qbuf, kvbuf, lens, partialO,
                                                mlbuf, attout);
  attn_combine<<<dim3(896), 256, 0, stream>>>(partialO, mlbuf, attout);

  o_gemm<<<dim3(8, 64), 256, 0, stream>>>(attout, WoT, bo, x, out);
}

// Round 11
// 105.790 us; speedup vs baseline: 2.5257x; 1.0231x over previous
//
#include <hip/hip_runtime.h>
#include <hip/hip_bf16.h>

typedef __attribute__((ext_vector_type(4))) float f32x4;
typedef __attribute__((ext_vector_type(16))) float f32x16;
typedef __attribute__((ext_vector_type(8))) short short8;

#define D_MODEL 512
#define SQ 2048
#define NH 8
#define NBATCH 4
#define MROWS (NBATCH * SQ)  // 8192

// split-K chunking: per qi (0..15), T=4*qi+4 tiles split into nch=(qi+2)>>1
// balanced chunks (sizes 4..8). Blocks per (n,h) = sum nch = 72.
#define CHUNKS_PER_NH 72
#define NSLOTS (32 * CHUNKS_PER_NH)  // 2304

__device__ __forceinline__ ushort f2b(float x) {
  unsigned int u = __float_as_uint(x);
  return (ushort)((u + 0x7fffu + ((u >> 16) & 1u)) >> 16);
}

__device__ __forceinline__ f32x4 mfma16(short8 a, short8 b, f32x4 c) {
  return __builtin_amdgcn_mfma_f32_16x16x32_bf16(a, b, c, 0, 0, 0);
}
__device__ __forceinline__ f32x16 mfma32(short8 a, short8 b, f32x16 c) {
  return __builtin_amdgcn_mfma_f32_32x32x16_bf16(a, b, c, 0, 0, 0);
}

#define GLOAD_LDS16(g, l)                                                      \
  __builtin_amdgcn_global_load_lds(                                            \
      (const __attribute__((address_space(1))) unsigned int*)(g),              \
      (__attribute__((address_space(3))) unsigned int*)(l), 16, 0, 0)

// ---------------------------------------------------------------------------
// Fused prep: weight transposes (blocks 0..1023) + LayerNorm (1024..3071).
// ---------------------------------------------------------------------------
__global__ __launch_bounds__(256) void prep_kernel(
    const float* __restrict__ Wq, const float* __restrict__ Wkv,
    const float* __restrict__ Wo, ushort* __restrict__ WT,
    ushort* __restrict__ WoT, const float* __restrict__ x,
    const float* __restrict__ gamma, const float* __restrict__ beta,
    ushort* __restrict__ xn) {
  if (blockIdx.x < 1024) {
    __shared__ ushort tile[32][33];
    int b = blockIdx.x;
    const float* W;
    ushort* D;
    int N;
    if (b < 256) {
      W = Wq; D = WT; N = 512;
    } else if (b < 768) {
      W = Wkv; D = WT + 512 * 512; N = 1024; b -= 256;
    } else {
      W = Wo; D = WoT; N = 512; b -= 768;
    }
    const int ntx = N >> 5;
    int n0 = (b % ntx) * 32, k0 = (b / ntx) * 32;
    int tx = threadIdx.x & 31, ty = threadIdx.x >> 5;
#pragma unroll
    for (int i = 0; i < 4; ++i) {
      int k = ty + i * 8;
      tile[tx][k] = f2b(W[(size_t)(k0 + k) * N + n0 + tx]);
    }
    __syncthreads();
#pragma unroll
    for (int i = 0; i < 4; ++i) {
      int nn = ty + i * 8;
      D[(size_t)(n0 + nn) * 512 + k0 + tx] = tile[nn][tx];
    }
    return;
  }

  // ---- LayerNorm part ----
  int wid = threadIdx.x >> 6, lane = threadIdx.x & 63;
  int row = (blockIdx.x - 1024) * 4 + wid;
  const float4* xr = (const float4*)(x + (size_t)row * D_MODEL);
  float4 v0 = xr[lane];
  float4 v1 = xr[lane + 64];
  float s = v0.x + v0.y + v0.z + v0.w + v1.x + v1.y + v1.z + v1.w;
  float q = v0.x * v0.x + v0.y * v0.y + v0.z * v0.z + v0.w * v0.w +
            v1.x * v1.x + v1.y * v1.y + v1.z * v1.z + v1.w * v1.w;
#pragma unroll
  for (int m = 1; m < 64; m <<= 1) {
    s += __shfl_xor(s, m, 64);
    q += __shfl_xor(q, m, 64);
  }
  float mu = s * (1.f / 512.f);
  float var = q * (1.f / 512.f) - mu * mu;
  float rs = rsqrtf(var + 1e-5f);
  const float4* g4 = (const float4*)gamma;
  const float4* b4 = (const float4*)beta;
  ushort* out = xn + (size_t)row * D_MODEL;
#pragma unroll
  for (int i = 0; i < 2; ++i) {
    float4 v = i ? v1 : v0;
    float4 gg = g4[lane + i * 64];
    float4 bb = b4[lane + i * 64];
    ushort4 o;
    o.x = f2b((v.x - mu) * rs * gg.x + bb.x);
    o.y = f2b((v.y - mu) * rs * gg.y + bb.y);
    o.z = f2b((v.z - mu) * rs * gg.z + bb.z);
    o.w = f2b((v.w - mu) * rs * gg.w + bb.w);
    *(ushort4*)(out + (lane + i * 64) * 4) = o;
  }
}

// ---------------------------------------------------------------------------
// Fused Q+KV projection GEMM (m97 structure) with dead-KV-tile skip.
// ---------------------------------------------------------------------------
__global__ __launch_bounds__(256) void qkv_gemm(
    const ushort* __restrict__ A, const ushort* __restrict__ BT,
    const float* __restrict__ bq, const float* __restrict__ bkv,
    ushort* __restrict__ qbuf, ushort* __restrict__ kvbuf, float qscale,
    const int* __restrict__ lens) {
  __shared__ __align__(16) ushort As[128 * 32];
  __shared__ __align__(16) ushort Bs[128 * 32];
  const int tid = threadIdx.x, lane = tid & 63, wid = tid >> 6;
  const int g = lane >> 4, r = lane & 15;
  const int wr = wid >> 1, wc = wid & 1;
  const int bm = blockIdx.y * 128, bn = blockIdx.x * 128;

  const bool isQ = (bn < 512);
  if (!isQ) {
    // dead KV tile skip: all rows of this tile >= len of its batch
    if ((bm & 2047) >= lens[bm >> 11]) return;
  }

  f32x4 acc[4][4];
#pragma unroll
  for (int a = 0; a < 4; ++a)
#pragma unroll
    for (int b = 0; b < 4; ++b) acc[a][b] = (f32x4){0.f, 0.f, 0.f, 0.f};

  const int srow = 32 * wid + (lane >> 2);
  const int scol = (lane & 3) * 8;
  const ushort* ga = A + (size_t)(bm + srow) * 512 + scol;
  const ushort* gb = BT + (size_t)(bn + srow) * 512 + scol;
  ushort* la = As + 32 * 32 * wid;
  ushort* lb = Bs + 32 * 32 * wid;

  for (int kb = 0; kb < 512; kb += 32) {
    __syncthreads();
    GLOAD_LDS16(ga + kb, la);
    GLOAD_LDS16(ga + kb + 16 * 512, la + 16 * 32);
    GLOAD_LDS16(gb + kb, lb);
    GLOAD_LDS16(gb + kb + 16 * 512, lb + 16 * 32);
    __syncthreads();
    short8 af[4], bf[4];
#pragma unroll
    for (int i2 = 0; i2 < 4; ++i2) {
      af[i2] = *(const short8*)&As[(wr * 64 + i2 * 16 + r) * 32 + g * 8];
      bf[i2] = *(const short8*)&Bs[(wc * 64 + i2 * 16 + r) * 32 + g * 8];
    }
#pragma unroll
    for (int a = 0; a < 4; ++a)
#pragma unroll
      for (int b = 0; b < 4; ++b) acc[a][b] = mfma16(af[a], bf[b], acc[a][b]);
  }

  const float* bias = isQ ? bq : bkv;
  ushort* dst = isQ ? qbuf : kvbuf;
  const int cb = isQ ? bn : bn - 512;
  const size_t stride = isQ ? 512 : 1024;
  const float scale = isQ ? qscale : 1.0f;

#pragma unroll
  for (int a = 0; a < 4; ++a) {
#pragma unroll
    for (int reg = 0; reg < 4; ++reg) {
      int row = bm + wr * 64 + a * 16 + g * 4 + reg;
#pragma unroll
      for (int b = 0; b < 4; ++b) {
        int col = cb + wc * 64 + b * 16 + r;
        dst[(size_t)row * stride + col] = f2b((acc[a][b][reg] + bias[col]) * scale);
      }
    }
  }
}

// ---------------------------------------------------------------------------
// Output-projection GEMM, fp32 out with residual. 64x64 tiles for max TLP:
// grid 8x128 = 1024 blocks = 4/CU = 16 waves/CU. 4 waves as 2x2 of 32x32
// output each (acc[2][2]); per-wave per-iter staging = 16 rows of A + B.
// ---------------------------------------------------------------------------
__global__ __launch_bounds__(256) void o_gemm(
    const ushort* __restrict__ A, const ushort* __restrict__ BT,
    const float* __restrict__ bias, const float* __restrict__ resid,
    float* __restrict__ outF) {
  __shared__ __align__(16) ushort As[64 * 32];
  __shared__ __align__(16) ushort Bs[64 * 32];
  const int tid = threadIdx.x, lane = tid & 63, wid = tid >> 6;
  const int g = lane >> 4, r = lane & 15;
  const int wr = wid >> 1, wc = wid & 1;
  const int bm = blockIdx.y * 64, bn = blockIdx.x * 64;

  f32x4 acc[2][2];
#pragma unroll
  for (int a = 0; a < 2; ++a)
#pragma unroll
    for (int b = 0; b < 2; ++b) acc[a][b] = (f32x4){0.f, 0.f, 0.f, 0.f};

  const int scol = (lane & 3) * 8;
  const int srow = 16 * wid + (lane >> 2);  // wave w stages rows [16w,16w+16)
  const ushort* ga = A + (size_t)(bm + srow) * 512 + scol;
  const ushort* gb = BT + (size_t)(bn + srow) * 512 + scol;
  ushort* la = As + 16 * 32 * wid;
  ushort* lb = Bs + 16 * 32 * wid;

  for (int kb = 0; kb < 512; kb += 32) {
    __syncthreads();
    GLOAD_LDS16(ga + kb, la);
    GLOAD_LDS16(gb + kb, lb);
    __syncthreads();
    short8 af[2], bf[2];
#pragma unroll
    for (int i2 = 0; i2 < 2; ++i2) {
      af[i2] = *(const short8*)&As[(wr * 32 + i2 * 16 + r) * 32 + g * 8];
      bf[i2] = *(const short8*)&Bs[(wc * 32 + i2 * 16 + r) * 32 + g * 8];
    }
#pragma unroll
    for (int a = 0; a < 2; ++a)
#pragma unroll
      for (int b = 0; b < 2; ++b) acc[a][b] = mfma16(af[a], bf[b], acc[a][b]);
  }

#pragma unroll
  for (int a = 0; a < 2; ++a) {
#pragma unroll
    for (int reg = 0; reg < 4; ++reg) {
      int row = bm + wr * 32 + a * 16 + g * 4 + reg;
#pragma unroll
      for (int b = 0; b < 2; ++b) {
        int col = bn + wc * 32 + b * 16 + r;
        outF[(size_t)row * 512 + col] =
            acc[a][b][reg] + bias[col] + resid[(size_t)row * 512 + col];
      }
    }
  }
}

// ---------------------------------------------------------------------------
// Flash attention, split-K (R3 core). Per (n,h): 72 chunk-blocks; 4 waves x
// 32 q-rows; 32-key tiles; depth-2 prefetched reg-staged K/V; XCD-balanced
// swizzle; LPT dispatch order. nch==1 groups (qi 0,1) write attout directly;
// others write partialO + (m,l) for the combine kernel.
// ---------------------------------------------------------------------------
__global__ __launch_bounds__(256) void attn_kernel(
    const ushort* __restrict__ qbuf, const ushort* __restrict__ kvbuf,
    const int* __restrict__ lengths, ushort* __restrict__ partialO,
    float2* __restrict__ mlbuf, ushort* __restrict__ attout) {
  __shared__ __align__(16) ushort smem[9728];
  // Kt buf b: smem + b*2304   ([32][72])
  // Vt buf b: smem + 4608 + b*2560  ([64][40], 16B-unit XOR swizzle)

  const int tid = threadIdx.x, lane = tid & 63, wid = tid >> 6;
  const int l31 = lane & 31, h = lane >> 5;

  const int bid = blockIdx.x;
  const int xcd = bid & 7;
  const int j = bid >> 3;          // 0..287
  const int grp = j / 72;          // batch index
  const int L = 71 - (j - grp * 72);  // chunk within (n,h), reversed (LPT)
  const int nh = (grp << 3) | xcd;
  const int n = nh >> 3, head = nh & 7;
  int qi = 0, c = L;
  while (c >= ((qi + 2) >> 1)) { c -= (qi + 2) >> 1; ++qi; }
  const int T = 4 * qi + 4, nch = (qi + 2) >> 1;
  const int t0 = (c * T) / nch;
  const int t1 = ((c + 1) * T) / nch;
  const int slot = nh * CHUNKS_PER_NH + L;

  const int qb = qi * 128;
  const int len = lengths[n];
  const int q0w = qb + 32 * wid;
  const int q_own = q0w + l31;
  const int nt_w_abs = 4 * qi + wid + 1;  // wave computes tiles t < this
  const int tlen = (len + 31) >> 5;
  int nt = min(t1, tlen) - t0;
  if (nt < 0) nt = 0;

  f32x16 o0, o1;
#pragma unroll
  for (int i = 0; i < 16; ++i) { o0[i] = 0.f; o1[i] = 0.f; }
  float m_ = -1e30f, ls = 0.f;

  const int skey = tid >> 3, sc8 = tid & 7;               // K staging
  const int kp = lane & 15, dvb = wid * 4 + (lane >> 4);  // V staging
  const int mu = (l31 >> 2) & 3;                          // V-unit swizzle key

  int voff[4];
#pragma unroll
  for (int jj = 0; jj < 4; ++jj) {
    int dv = 4 * dvb + jj;
    voff[jj] = dv * 20 + (((kp >> 2) ^ ((dv >> 2) & 3)) << 2) + (kp & 3);
  }

  const ushort* kvbase = kvbuf + (size_t)n * SQ * 1024 + head * 64;
  const ushort* kSrc = kvbase + (size_t)(t0 * 32 + skey) * 1024 + sc8 * 8;
  const ushort* vSrc = kvbase + 512 + (size_t)(t0 * 32 + 2 * kp) * 1024 + dvb * 4;
  const int kLdsOff = skey * 72 + sc8 * 8;

  if (nt > 0) {
    // Q fragments (persistent): B-frag col=q=l31, k = 16kc + 8h + e
    short8 qf[4];
    {
      const ushort* qp = qbuf + (size_t)(n * SQ + q_own) * 512 + head * 64 + 8 * h;
#pragma unroll
      for (int kc = 0; kc < 4; ++kc) qf[kc] = *(const short8*)(qp + 16 * kc);
    }

    // two register staging sets; tile t lives in set (t-t0)&1
    uint4 kA, kB = {};
    uint2 vaA, vbA, vaB = {}, vbB = {};
    kA = *(const uint4*)kSrc;
    vaA = *(const uint2*)vSrc;
    vbA = *(const uint2*)(vSrc + 1024);
    kSrc += 32 * 1024;
    vSrc += 32 * 1024;
    if (nt > 1) {
      kB = *(const uint4*)kSrc;
      vaB = *(const uint2*)vSrc;
      vbB = *(const uint2*)(vSrc + 1024);
      kSrc += 32 * 1024;
      vSrc += 32 * 1024;
    }
    {  // write tile 0 (set A) into buffer 0
      *(uint4*)(smem + kLdsOff) = kA;
      const ushort* a16 = (const ushort*)&vaA;
      const ushort* b16 = (const ushort*)&vbA;
#pragma unroll
      for (int jj = 0; jj < 4; ++jj)
        ((unsigned*)(smem + 4608))[voff[jj]] =
            (unsigned)a16[jj] | ((unsigned)b16[jj] << 16);
    }
    __syncthreads();

    for (int i = 0; i < nt; ++i) {
      const int t = t0 + i;
      const int cur = i & 1;
      if (i + 2 < nt) {  // issue loads 2 tiles ahead into the freed set
        if (cur == 0) {
          kA = *(const uint4*)kSrc;
          vaA = *(const uint2*)vSrc;
          vbA = *(const uint2*)(vSrc + 1024);
        } else {
          kB = *(const uint4*)kSrc;
          vaB = *(const uint2*)vSrc;
          vbB = *(const uint2*)(vSrc + 1024);
        }
        kSrc += 32 * 1024;
        vSrc += 32 * 1024;
      }

      if (t < nt_w_abs) {
        const int kb = t * 32;
        const ushort* KtB = smem + cur * 2304;
        const ushort* VtB = smem + 4608 + cur * 2560;

        // QK^T swapped: S^T[key][q], col=q=l31, key(reg)=(reg&3)+8*(reg>>2)+4h
        f32x16 s;
#pragma unroll
        for (int i2 = 0; i2 < 16; ++i2) s[i2] = 0.f;
        {
          const ushort* kr_ = KtB + l31 * 72 + 8 * h;
          short8 k0 = *(const short8*)(kr_);
          short8 k1 = *(const short8*)(kr_ + 16);
          short8 k2 = *(const short8*)(kr_ + 32);
          short8 k3 = *(const short8*)(kr_ + 48);
          __builtin_amdgcn_s_setprio(1);
          s = mfma32(k0, qf[0], s);
          s = mfma32(k1, qf[1], s);
          s = mfma32(k2, qf[2], s);
          s = mfma32(k3, qf[3], s);
          __builtin_amdgcn_s_setprio(0);
        }

        // boundary tiles only: causal + length mask
        if (kb + 31 > q0w || kb + 31 >= len) {
          int keyb = kb + 4 * h;
#pragma unroll
          for (int reg = 0; reg < 16; ++reg) {
            int key = keyb + (reg & 3) + 8 * (reg >> 2);
            bool ok = (key <= q_own) && (key < len);
            s[reg] = ok ? s[reg] : -1e30f;
          }
        }

        // max-reduce as v_max3-fusable tree
        float a0 = fmaxf(fmaxf(s[0], s[1]), s[2]);
        float a1 = fmaxf(fmaxf(s[3], s[4]), s[5]);
        float a2 = fmaxf(fmaxf(s[6], s[7]), s[8]);
        float a3 = fmaxf(fmaxf(s[9], s[10]), s[11]);
        float a4 = fmaxf(fmaxf(s[12], s[13]), s[14]);
        float mx = fmaxf(fmaxf(fmaxf(a0, a1), s[15]),
                         fmaxf(fmaxf(a2, a3), a4));
        {
          auto rr = __builtin_amdgcn_permlane32_swap(__float_as_uint(mx),
                                                     __float_as_uint(mx), false, false);
          mx = fmaxf(__uint_as_float(((const unsigned*)&rr)[0]),
                     __uint_as_float(((const unsigned*)&rr)[1]));
        }

        if (!__all(mx <= m_ + 8.0f)) {
          float mn = fmaxf(m_, mx);
          float sf = __builtin_amdgcn_exp2f(m_ - mn);
          m_ = mn;
          ls *= sf;
#pragma unroll
          for (int i2 = 0; i2 < 16; ++i2) { o0[i2] *= sf; o1[i2] *= sf; }
        }

        float p[16];
#pragma unroll
        for (int reg = 0; reg < 16; ++reg)
          p[reg] = __builtin_amdgcn_exp2f(s[reg] - m_);

        float rsum = ((p[0] + p[1]) + (p[2] + p[3])) + ((p[4] + p[5]) + (p[6] + p[7])) +
                     ((p[8] + p[9]) + (p[10] + p[11])) +
                     ((p[12] + p[13]) + (p[14] + p[15]));
        {
          auto rr = __builtin_amdgcn_permlane32_swap(__float_as_uint(rsum),
                                                     __float_as_uint(rsum), false, false);
          rsum = __uint_as_float(((const unsigned*)&rr)[0]) +
                 __uint_as_float(((const unsigned*)&rr)[1]);
        }
        ls += rsum;

        unsigned pk[8];
#pragma unroll
        for (int jj = 0; jj < 8; ++jj)
          pk[jj] = __builtin_amdgcn_perm(__float_as_uint(p[2 * jj + 1]),
                                         __float_as_uint(p[2 * jj]), 0x07060302u);

        // PV: B-frag = own pk words (k-slot sigma(h,e)=16kc+4h+(e&3)+8(e>>2))
        __builtin_amdgcn_s_setprio(1);
#pragma unroll
        for (int kc = 0; kc < 2; ++kc) {
          short8 pf;
          ((unsigned*)&pf)[0] = pk[4 * kc + 0];
          ((unsigned*)&pf)[1] = pk[4 * kc + 1];
          ((unsigned*)&pf)[2] = pk[4 * kc + 2];
          ((unsigned*)&pf)[3] = pk[4 * kc + 3];
          const int u0 = ((2 * kc) ^ mu) << 3;
          const ushort* vb0 = VtB + l31 * 40 + 4 * h;
          const ushort* vb1 = VtB + (32 + l31) * 40 + 4 * h;
          short8 vf0, vf1;
          ((uint2*)&vf0)[0] = *(const uint2*)(vb0 + u0);
          ((uint2*)&vf0)[1] = *(const uint2*)(vb0 + (u0 ^ 8));
          ((uint2*)&vf1)[0] = *(const uint2*)(vb1 + u0);
          ((uint2*)&vf1)[1] = *(const uint2*)(vb1 + (u0 ^ 8));
          o0 = mfma32(vf0, pf, o0);
          o1 = mfma32(vf1, pf, o1);
        }
        __builtin_amdgcn_s_setprio(0);
      }

      if (i + 1 < nt) {  // write tile i+1's regs (in flight ~1 iteration)
        ushort* KtN = smem + (cur ^ 1) * 2304;
        unsigned* VtN = (unsigned*)(smem + 4608 + (cur ^ 1) * 2560);
        if (cur == 0) {
          *(uint4*)(KtN + kLdsOff) = kB;
          const ushort* a16 = (const ushort*)&vaB;
          const ushort* b16 = (const ushort*)&vbB;
#pragma unroll
          for (int jj = 0; jj < 4; ++jj)
            VtN[voff[jj]] = (unsigned)a16[jj] | ((unsigned)b16[jj] << 16);
        } else {
          *(uint4*)(KtN + kLdsOff) = kA;
          const ushort* a16 = (const ushort*)&vaA;
          const ushort* b16 = (const ushort*)&vbA;
#pragma unroll
          for (int jj = 0; jj < 4; ++jj)
            VtN[voff[jj]] = (unsigned)a16[jj] | ((unsigned)b16[jj] << 16);
        }
      }
      __syncthreads();
    }
  }

  // epilogue: normalize partial, transpose via LDS, store.
  const unsigned long long alive = __ballot(ls > 0.f);
  {
    float inv = (ls > 0.f) ? 1.f / ls : 0.f;
    ushort* OtW = smem + wid * (32 * 68);
#pragma unroll
    for (int b = 0; b < 2; ++b) {
#pragma unroll
      for (int reg = 0; reg < 16; reg += 2) {
        float e0 = (b ? o1[reg] : o0[reg]) * inv;
        float e1 = (b ? o1[reg + 1] : o0[reg + 1]) * inv;
        unsigned pko = __builtin_amdgcn_perm(__float_as_uint(e1),
                                             __float_as_uint(e0), 0x07060302u);
        int dv = 32 * b + (reg & 3) + 8 * (reg >> 2) + 4 * h;
        *(unsigned*)(OtW + l31 * 68 + dv) = pko;
      }
    }
    if (h == 0 && nch > 1)
      mlbuf[slot * 128 + 32 * wid + l31] = make_float2(m_, ls);
  }
  __syncthreads();

  if (nch == 1) {
    // qi 0/1: single chunk covers keys from 0; all rows live. Direct store.
    int r = lane >> 1, sg = lane & 1;
    const ushort* rp = smem + wid * (32 * 68) + r * 68 + sg * 32;
    uint2 d0 = *(const uint2*)(rp);
    uint2 d1 = *(const uint2*)(rp + 4);
    uint2 d2 = *(const uint2*)(rp + 8);
    uint2 d3 = *(const uint2*)(rp + 12);
    uint2 d4 = *(const uint2*)(rp + 16);
    uint2 d5 = *(const uint2*)(rp + 20);
    uint2 d6 = *(const uint2*)(rp + 24);
    uint2 d7 = *(const uint2*)(rp + 28);
    ushort* gp = attout + (size_t)(n * SQ + qb + 32 * wid + r) * 512 +
                 head * 64 + sg * 32;
    *(uint4*)(gp) = make_uint4(d0.x, d0.y, d1.x, d1.y);
    *(uint4*)(gp + 8) = make_uint4(d2.x, d2.y, d3.x, d3.y);
    *(uint4*)(gp + 16) = make_uint4(d4.x, d4.y, d5.x, d5.y);
    *(uint4*)(gp + 24) = make_uint4(d6.x, d6.y, d7.x, d7.y);
    return;
  }

  if (alive) {
    int r = lane >> 1, sg = lane & 1;
    if ((alive >> r) & 1ULL) {
      const ushort* rp = smem + wid * (32 * 68) + r * 68 + sg * 32;
      uint2 d0 = *(const uint2*)(rp);
      uint2 d1 = *(const uint2*)(rp + 4);
      uint2 d2 = *(const uint2*)(rp + 8);
      uint2 d3 = *(const uint2*)(rp + 12);
      uint2 d4 = *(const uint2*)(rp + 16);
      uint2 d5 = *(const uint2*)(rp + 20);
      uint2 d6 = *(const uint2*)(rp + 24);
      uint2 d7 = *(const uint2*)(rp + 28);
      ushort* gp = partialO + (size_t)slot * 8192 + (32 * wid + r) * 64 + sg * 32;
      *(uint4*)(gp) = make_uint4(d0.x, d0.y, d1.x, d1.y);
      *(uint4*)(gp + 8) = make_uint4(d2.x, d2.y, d3.x, d3.y);
      *(uint4*)(gp + 16) = make_uint4(d4.x, d4.y, d5.x, d5.y);
      *(uint4*)(gp + 24) = make_uint4(d6.x, d6.y, d7.x, d7.y);
    }
  }
}

// ---------------------------------------------------------------------------
// Split-K combine for qi >= 2 (nch 2..8). One block per (nh, qi, rowhalf);
// each thread merges 16 floats.
// ---------------------------------------------------------------------------
__global__ __launch_bounds__(256) void attn_combine(
    const ushort* __restrict__ partialO, const float2* __restrict__ mlbuf,
    ushort* __restrict__ attout) {
  const int bx = blockIdx.x;  // (group, rowhalf)
  const int gidx = bx >> 1, rowhalf = bx & 1;
  const int nh = gidx / 14, qi = 2 + (gidx % 14);
  const int nch = (qi + 2) >> 1;                       // 2..8 chunks
  const int off = (qi * (qi + 2) + (qi & 1)) >> 2;     // sum_{j<qi} (j+2)>>1
  const int n = nh >> 3, head = nh & 7;
  const int slot0 = nh * CHUNKS_PER_NH + off;

  const int tid = threadIdx.x;
  const int r = rowhalf * 64 + (tid >> 2);  // 0..127
  const int quarter = tid & 3;              // 16-col slice

  float mstar = -1e30f;
  for (int c = 0; c < nch; ++c) {
    float2 ml = mlbuf[(slot0 + c) * 128 + r];
    mstar = fmaxf(mstar, ml.x);
  }

  float acc[16];
#pragma unroll
  for (int j = 0; j < 16; ++j) acc[j] = 0.f;
  float Lsum = 0.f;

  for (int c = 0; c < nch; ++c) {
    float2 ml = mlbuf[(slot0 + c) * 128 + r];
    if (ml.y > 0.f) {
      float cf = ml.y * __builtin_amdgcn_exp2f(ml.x - mstar);
      Lsum += cf;
      const uint4* p =
          (const uint4*)(partialO + (size_t)(slot0 + c) * 8192 + r * 64 + quarter * 16);
#pragma unroll
      for (int u = 0; u < 2; ++u) {
        uint4 d = p[u];
        unsigned w[4] = {d.x, d.y, d.z, d.w};
#pragma unroll
        for (int k = 0; k < 4; ++k) {
          acc[u * 8 + 2 * k] += cf * __uint_as_float(w[k] << 16);
          acc[u * 8 + 2 * k + 1] += cf * __uint_as_float(w[k] & 0xffff0000u);
        }
      }
    }
  }

  const float inv = 1.f / Lsum;
  uint4 outw[2];
#pragma unroll
  for (int u = 0; u < 2; ++u) {
    unsigned ww[4];
#pragma unroll
    for (int k = 0; k < 4; ++k) {
      float e0 = acc[u * 8 + 2 * k] * inv;
      float e1 = acc[u * 8 + 2 * k + 1] * inv;
      ww[k] = ((unsigned)f2b(e0)) | (((unsigned)f2b(e1)) << 16);
    }
    outw[u] = make_uint4(ww[0], ww[1], ww[2], ww[3]);
  }
  ushort* gp = attout + (size_t)(n * SQ + qi * 128 + r) * 512 + head * 64 + quarter * 16;
  ((uint4*)gp)[0] = outw[0];
  ((uint4*)gp)[1] = outw[1];
}

// ---------------------------------------------------------------------------
extern "C" void kernel_launch(void* const* d_in, const int* in_sizes, int n_in,
                              void* d_out, int out_size, void* d_ws, size_t ws_size,
                              hipStream_t stream) {
  const float* x = (const float*)d_in[0];
  const int* lens = (const int*)d_in[1];
  const float* Wq = (const float*)d_in[2];
  const float* bq = (const float*)d_in[3];
  const float* Wkv = (const float*)d_in[4];
  const float* bkv = (const float*)d_in[5];
  const float* Wo = (const float*)d_in[6];
  const float* bo = (const float*)d_in[7];
  const float* gamma = (const float*)d_in[8];
  const float* beta = (const float*)d_in[9];
  float* out = (float*)d_out;

  size_t off = 0;
  auto alloc = [&](size_t bytes) {
    void* p = (char*)d_ws + off;
    off += (bytes + 255) & ~(size_t)255;
    return p;
  };
  ushort* xn = (ushort*)alloc((size_t)MROWS * 512 * 2);
  ushort* qbuf = (ushort*)alloc((size_t)MROWS * 512 * 2);
  ushort* kvbuf = (ushort*)alloc((size_t)MROWS * 1024 * 2);
  ushort* WT = (ushort*)alloc((size_t)1536 * 512 * 2);  // [Wq^T ; Wkv^T]
  ushort* WoT = (ushort*)alloc((size_t)512 * 512 * 2);
  ushort* partialO = (ushort*)alloc((size_t)NSLOTS * 8192 * 2);  // 37.7 MB
  float2* mlbuf = (float2*)alloc((size_t)NSLOTS * 128 * 8);      // 2.4 MB
  ushort* attout = xn;  // xn dead after the QKV GEMM (stream-ordered)

  prep_kernel<<<dim3(1024 + MROWS / 4), 256, 0, stream>>>(
      Wq, Wkv, Wo, WT, WoT, x, gamma, beta, xn);

  // Q pre-scaled by 1/sqrt(dq) * log2(e) so attention uses exp2 directly
  qkv_gemm<<<dim3(12, 64), 256, 0, stream>>>(xn, WT, bq, bkv, qbuf, kvbuf,
                                             0.125f * 1.44269504f, lens);

  attn_kernel<<<dim3(NSLOTS), 256, 0, stream>>>(qbuf, kvbuf, lens, partialO,
                                                mlbuf, attout);
  attn_combine<<<dim3(896), 256, 0, stream>>>(partialO, mlbuf, attout);

  o_gemm<<<dim3(8, 128), 256, 0, stream>>>(attout, WoT, bo, x, out);
}